// Round 1
// baseline (58959.155 us; speedup 1.0000x reference)
//
#include <hip/hip_runtime.h>
#include <math.h>

#define BB 512
#define TT 256
#define DD 128
#define HH 256
#define OO 128
#define KH 640   // 3*D + H

__device__ __forceinline__ float sigmoidf_(float x){ return 1.0f/(1.0f+__expf(-x)); }

// ---------------- Kernel 1: x1 = x @ W_emb^T + b_emb ----------------
__global__ __launch_bounds__(128) void k_emb(const float* __restrict__ x,
                                             const float* __restrict__ W,
                                             const float* __restrict__ bias,
                                             float* __restrict__ x1){
    __shared__ __align__(16) float xs[8][DD];
    const int j = threadIdx.x;
    const long row0 = (long)blockIdx.x * 32;
    const float bj = bias[j];
    const float4* W4 = (const float4*)(W + j*DD);
    for(int g=0; g<4; ++g){
        const long rbase = row0 + g*8;
        for(int r=0;r<8;++r) xs[r][j] = x[(rbase+r)*DD + j];
        __syncthreads();
        float acc[8];
        #pragma unroll
        for(int r=0;r<8;++r) acc[r] = bj;
        for(int k4=0;k4<DD/4;++k4){
            float4 w = W4[k4];
            #pragma unroll
            for(int r=0;r<8;++r){
                float4 c = ((const float4*)xs[r])[k4];
                acc[r] += c.x*w.x + c.y*w.y + c.z*w.z + c.w*w.w;
            }
        }
        for(int r=0;r<8;++r) x1[(rbase+r)*DD + j] = acc[r];
        __syncthreads();
    }
}

// ---------------- Kernel 2: x_mean = mean_t(x1) ----------------
__global__ __launch_bounds__(128) void k_mean(const float* __restrict__ x1,
                                              float* __restrict__ xmean){
    const int j = threadIdx.x;
    const int b = blockIdx.x;
    const float* p = x1 + (long)b*TT*DD + j;
    float s = 0.f;
    for(int t=0;t<TT;++t) s += p[(long)t*DD];
    xmean[b*DD + j] = s * (1.0f/TT);
}

// ---------------- Kernel 3: gamma/conf/x_final (in-place on x1) ----------------
__global__ __launch_bounds__(128) void k_gate(float* __restrict__ xf,
    const float* __restrict__ xmask, const float* __restrict__ xdelta,
    const float* __restrict__ noise,
    const float* __restrict__ Wd1, const float* __restrict__ bd1,
    const float* __restrict__ Wd2, const float* __restrict__ bd2,
    const float* __restrict__ Wc,  const float* __restrict__ bc,
    const float* __restrict__ xmean){
    __shared__ __align__(16) float ds[8][DD];
    __shared__ __align__(16) float t1s[8][DD];
    __shared__ __align__(16) float xhs[8][DD];
    const int j = threadIdx.x;
    const long row0 = (long)blockIdx.x * 32;
    const int b = (int)(row0 >> 8);   // 256 rows (t) per batch element
    const float xm = xmean[b*DD + j];
    const float b1 = bd1[j], b2 = bd2[j], bcj = bc[j];
    const float4* Wd1_4 = (const float4*)(Wd1 + j*DD);
    const float4* Wd2_4 = (const float4*)(Wd2 + j*DD);
    const float4* Wc_4  = (const float4*)(Wc  + j*2*DD);
    for(int g=0; g<4; ++g){
        const long rbase = row0 + g*8;
        for(int r=0;r<8;++r)
            ds[r][j] = fminf(fmaxf(xdelta[(rbase+r)*DD + j], 0.f), 100.f);
        __syncthreads();
        float acc[8];
        // t1 = relu(d @ Wd1^T + b1)
        #pragma unroll
        for(int r=0;r<8;++r) acc[r] = b1;
        for(int k4=0;k4<DD/4;++k4){
            float4 w = Wd1_4[k4];
            #pragma unroll
            for(int r=0;r<8;++r){
                float4 c = ((const float4*)ds[r])[k4];
                acc[r] += c.x*w.x + c.y*w.y + c.z*w.z + c.w*w.w;
            }
        }
        for(int r=0;r<8;++r) t1s[r][j] = fmaxf(acc[r], 0.f);
        __syncthreads();
        // gamma = sigmoid(t1 @ Wd2^T + b2); x_hat
        #pragma unroll
        for(int r=0;r<8;++r) acc[r] = b2;
        for(int k4=0;k4<DD/4;++k4){
            float4 w = Wd2_4[k4];
            #pragma unroll
            for(int r=0;r<8;++r){
                float4 c = ((const float4*)t1s[r])[k4];
                acc[r] += c.x*w.x + c.y*w.y + c.z*w.z + c.w*w.w;
            }
        }
        for(int r=0;r<8;++r){
            float gmm = sigmoidf_(acc[r]);
            float m  = xmask[(rbase+r)*DD + j];
            float xv = xf[(rbase+r)*DD + j];
            xhs[r][j] = m*xv + (1.f-m)*gmm*xm;
        }
        __syncthreads();
        // conf = sigmoid([x_hat, d] @ Wc^T + bc); x_final
        #pragma unroll
        for(int r=0;r<8;++r) acc[r] = bcj;
        for(int k4=0;k4<DD/4;++k4){
            float4 w = Wc_4[k4];
            #pragma unroll
            for(int r=0;r<8;++r){
                float4 c = ((const float4*)xhs[r])[k4];
                acc[r] += c.x*w.x + c.y*w.y + c.z*w.z + c.w*w.w;
            }
        }
        for(int k4=0;k4<DD/4;++k4){
            float4 w = Wc_4[DD/4 + k4];
            #pragma unroll
            for(int r=0;r<8;++r){
                float4 c = ((const float4*)ds[r])[k4];
                acc[r] += c.x*w.x + c.y*w.y + c.z*w.z + c.w*w.w;
            }
        }
        for(int r=0;r<8;++r){
            float conf = sigmoidf_(acc[r]);
            float xh = xhs[r][j];
            float nz = noise[(rbase+r)*DD + j];
            xf[(rbase+r)*DD + j] = xh*conf + nz*(1.f-conf);
        }
        __syncthreads();
    }
}

// ---------------- Kernel 4: GRU recurrence (4 batch rows / block) ----------------
__global__ __launch_bounds__(1024) void k_gru(const float* __restrict__ xf,
    const float* __restrict__ xmask, const float* __restrict__ xdelta,
    const float* __restrict__ Wz, const float* __restrict__ bz,
    const float* __restrict__ Wr, const float* __restrict__ br,
    const float* __restrict__ Wh, const float* __restrict__ bh,
    float* __restrict__ hout){
    // xc row layout: [0:128)=x_final  [128:256)=mask  [256:384)=d  [384:640)=h
    __shared__ __align__(16) float xc[4][KH];
    __shared__ __align__(16) float rh[4][HH];
    const int tid = threadIdx.x;
    const int j  = tid & 255;
    const int bl = tid >> 8;          // 0..3 : which batch row this thread works on
    const long bbase = (long)blockIdx.x * 4;

    xc[bl][384 + j] = 0.f;            // h0 = 0
    const float bzj = bz[j], brj = br[j], bhj = bh[j];
    const float4* Wz4 = (const float4*)(Wz + (long)j*KH);
    const float4* Wr4 = (const float4*)(Wr + (long)j*KH);
    const float4* Wh4 = (const float4*)(Wh + (long)j*KH);
    __syncthreads();

    for(int t=0;t<TT;++t){
        // stage x_final/mask/d rows for the 4 batch elements (512 threads active)
        if(tid < 4*DD){
            int sb = tid >> 7, k = tid & 127;
            long row = (bbase + sb)*TT + t;
            xc[sb][k]       = xf[row*DD + k];
            xc[sb][128 + k] = xmask[row*DD + k];
            xc[sb][256 + k] = fminf(fmaxf(xdelta[row*DD + k], 0.f), 100.f);
        }
        __syncthreads();

        // phase A: z and r gates (full K=640 dot incl. h)
        const float4* cb = (const float4*)xc[bl];
        float az = bzj, ar = brj;
        for(int k4=0;k4<KH/4;++k4){
            float4 wz = Wz4[k4], wr = Wr4[k4];
            float4 v = cb[k4];
            az += v.x*wz.x + v.y*wz.y + v.z*wz.z + v.w*wz.w;
            ar += v.x*wr.x + v.y*wr.y + v.z*wr.z + v.w*wr.w;
        }
        float z = sigmoidf_(az);
        float r = sigmoidf_(ar);
        rh[bl][j] = r * xc[bl][384 + j];
        __syncthreads();

        // phase B: h_tilde (K=384 on xc, K=256 on r*h)
        float ah = bhj;
        for(int k4=0;k4<96;++k4){
            float4 wh = Wh4[k4];
            float4 v = cb[k4];
            ah += v.x*wh.x + v.y*wh.y + v.z*wh.z + v.w*wh.w;
        }
        const float4* rp = (const float4*)rh[bl];
        for(int k4=0;k4<64;++k4){
            float4 wh = Wh4[96 + k4];
            float4 v = rp[k4];
            ah += v.x*wh.x + v.y*wh.y + v.z*wh.z + v.w*wh.w;
        }
        float ht = tanhf(ah);
        float hold = xc[bl][384 + j];
        float hn = (1.f - z)*hold + z*ht;
        // safe: phase B reads only xc[][0:384), rh, and this thread's own h element
        xc[bl][384 + j] = hn;
        __syncthreads();
    }
    // write h_last
    hout[(bbase + bl)*HH + j] = xc[bl][384 + j];
}

// ---------------- Kernel 5: LayerNorm + output projection ----------------
__global__ __launch_bounds__(256) void k_lnout(const float* __restrict__ hbuf,
    const float* __restrict__ lng, const float* __restrict__ lnb,
    const float* __restrict__ Wo, const float* __restrict__ bo,
    float* __restrict__ out){
    __shared__ __align__(16) float ln_s[HH];
    __shared__ float red[8];
    const int b = blockIdx.x, j = threadIdx.x;
    const float v = hbuf[(long)b*HH + j];
    float s = v, ss = v*v;
    const int lane = j & 63, w = j >> 6;
    for(int off=32; off>0; off>>=1){
        s  += __shfl_down(s,  off);
        ss += __shfl_down(ss, off);
    }
    if(lane == 0){ red[w] = s; red[4+w] = ss; }
    __syncthreads();
    float tot  = red[0]+red[1]+red[2]+red[3];
    float tot2 = red[4]+red[5]+red[6]+red[7];
    float mu  = tot  * (1.0f/HH);
    float var = tot2 * (1.0f/HH) - mu*mu;
    float rstd = rsqrtf(var + 1e-5f);
    ln_s[j] = (v - mu)*rstd*lng[j] + lnb[j];
    __syncthreads();
    if(j < OO){
        float acc = bo[j];
        const float4* w4 = (const float4*)(Wo + j*HH);
        const float4* l4 = (const float4*)ln_s;
        for(int k4=0;k4<HH/4;++k4){
            float4 wv = w4[k4], c = l4[k4];
            acc += wv.x*c.x + wv.y*c.y + wv.z*c.z + wv.w*c.w;
        }
        out[(long)b*OO + j] = acc;
    }
}

extern "C" void kernel_launch(void* const* d_in, const int* in_sizes, int n_in,
                              void* d_out, int out_size, void* d_ws, size_t ws_size,
                              hipStream_t stream){
    const float* x      = (const float*)d_in[0];
    const float* xmask  = (const float*)d_in[1];
    const float* xdelta = (const float*)d_in[2];
    const float* noise  = (const float*)d_in[3];
    const float* W_emb  = (const float*)d_in[4];
    const float* b_emb  = (const float*)d_in[5];
    const float* W_d1   = (const float*)d_in[6];
    const float* b_d1   = (const float*)d_in[7];
    const float* W_d2   = (const float*)d_in[8];
    const float* b_d2   = (const float*)d_in[9];
    const float* W_c    = (const float*)d_in[10];
    const float* b_c    = (const float*)d_in[11];
    const float* W_z    = (const float*)d_in[12];
    const float* b_z    = (const float*)d_in[13];
    const float* W_r    = (const float*)d_in[14];
    const float* b_r    = (const float*)d_in[15];
    const float* W_h    = (const float*)d_in[16];
    const float* b_h    = (const float*)d_in[17];
    const float* ln_g   = (const float*)d_in[18];
    const float* ln_b   = (const float*)d_in[19];
    const float* W_o    = (const float*)d_in[20];
    const float* b_o    = (const float*)d_in[21];
    float* out = (float*)d_out;

    char* ws = (char*)d_ws;
    float* xf    = (float*)ws;                                        // B*T*D f32 (x1 then x_final)
    float* xmean = (float*)(ws + (size_t)BB*TT*DD*4);                 // B*D
    float* hbuf  = (float*)(ws + (size_t)BB*TT*DD*4 + (size_t)BB*DD*4); // B*H

    k_emb  <<<dim3(BB*TT/32), dim3(128), 0, stream>>>(x, W_emb, b_emb, xf);
    k_mean <<<dim3(BB),       dim3(128), 0, stream>>>(xf, xmean);
    k_gate <<<dim3(BB*TT/32), dim3(128), 0, stream>>>(xf, xmask, xdelta, noise,
                                                      W_d1,b_d1,W_d2,b_d2,W_c,b_c, xmean);
    k_gru  <<<dim3(BB/4),     dim3(1024),0, stream>>>(xf, xmask, xdelta,
                                                      W_z,b_z,W_r,b_r,W_h,b_h, hbuf);
    k_lnout<<<dim3(BB),       dim3(256), 0, stream>>>(hbuf, ln_g, ln_b, W_o, b_o, out);
}

// Round 2
// 58877.820 us; speedup vs baseline: 1.0014x; 1.0014x over previous
//
#include <hip/hip_runtime.h>
#include <hip/hip_fp16.h>
#include <math.h>

#define BB 512
#define TT 256
#define DD 128
#define HH 256
#define OO 128
#define KH 640   // 3*D + H
#define BT (BB*TT)

typedef unsigned int uint_t;

__device__ __forceinline__ float sigmoidf_(float x){ return 1.0f/(1.0f+__expf(-x)); }
__device__ __forceinline__ float tanhf_(float x){ float e = __expf(-2.0f*x); return 2.0f/(1.0f+e) - 1.0f; }

// packed-f16 dot2 with f32 accumulator
typedef _Float16 h2v __attribute__((ext_vector_type(2)));
__device__ __forceinline__ float d2(uint_t a, uint_t b, float c){
#if __has_builtin(__builtin_amdgcn_fdot2)
    return __builtin_amdgcn_fdot2(__builtin_bit_cast(h2v, a), __builtin_bit_cast(h2v, b), c, false);
#else
    __half2 ha = __builtin_bit_cast(__half2, a);
    __half2 hb = __builtin_bit_cast(__half2, b);
    return c + __half2float(ha.x)*__half2float(hb.x) + __half2float(ha.y)*__half2float(hb.y);
#endif
}

// ================= new path =================

// ---- ws layout (bytes) ----
static const size_t SZ_PXH  = (size_t)BT*768*2;      // 201326592  (x1h aliases its head)
static const size_t OFF_PXH = 0;
static const size_t OFF_X1H = 0;                      // BT*128*2 = 33554432, dead before pxh written
static const size_t OFF_XCH = SZ_PXH;                 // BT*384*2 = 100663296
static const size_t OFF_WCAT  = OFF_XCH + (size_t)BT*384*2;      // 768*384*2
static const size_t OFF_WREC  = OFF_WCAT + (size_t)768*384*2;    // 768*256*2
static const size_t OFF_BCAT  = OFF_WREC + (size_t)768*256*2;    // 768*4
static const size_t OFF_XMEAN = OFF_BCAT + (size_t)768*4;        // 512*128*4
static const size_t OFF_HBUF  = OFF_XMEAN + (size_t)BB*DD*4;     // 512*256*4
static const size_t WS_NEED   = OFF_HBUF + (size_t)BB*HH*4;

// ---- weight prep: f32 -> f16, split cat(384) / rec(256) ----
__global__ __launch_bounds__(128) void k_wprep(const float* __restrict__ Wz, const float* __restrict__ Wr,
                                               const float* __restrict__ Wh, const float* __restrict__ bz,
                                               const float* __restrict__ br, const float* __restrict__ bh,
                                               __half* __restrict__ Wcat, __half* __restrict__ Wrec,
                                               float* __restrict__ bcat){
    int gj = blockIdx.x; int j = gj & 255;
    const float* src  = (gj < 256 ? Wz : (gj < 512 ? Wr : Wh)) + (size_t)j*KH;
    const float* bsrc = (gj < 256 ? bz : (gj < 512 ? br : bh));
    for(int k=threadIdx.x; k<384; k+=128) Wcat[(size_t)gj*384 + k] = __float2half(src[k]);
    for(int k=threadIdx.x; k<256; k+=128) Wrec[(size_t)gj*256 + k] = __float2half(src[384+k]);
    if(threadIdx.x==0) bcat[gj] = bsrc[j];
}

// ---- x1 = x @ W_emb^T + b  (f16 out) ----
__global__ __launch_bounds__(128) void k_emb(const float* __restrict__ x,
                                             const float* __restrict__ W,
                                             const float* __restrict__ bias,
                                             __half* __restrict__ x1h){
    __shared__ __align__(16) float xs[8][DD];
    const int j = threadIdx.x;
    const long row0 = (long)blockIdx.x * 32;
    const float bj = bias[j];
    const float4* W4 = (const float4*)(W + j*DD);
    for(int g=0; g<4; ++g){
        const long rbase = row0 + g*8;
        for(int r=0;r<8;++r) xs[r][j] = x[(rbase+r)*DD + j];
        __syncthreads();
        float acc[8];
        #pragma unroll
        for(int r=0;r<8;++r) acc[r] = bj;
        for(int k4=0;k4<DD/4;++k4){
            float4 w = W4[k4];
            #pragma unroll
            for(int r=0;r<8;++r){
                float4 c = ((const float4*)xs[r])[k4];
                acc[r] += c.x*w.x + c.y*w.y + c.z*w.z + c.w*w.w;
            }
        }
        for(int r=0;r<8;++r) x1h[(rbase+r)*DD + j] = __float2half(acc[r]);
        __syncthreads();
    }
}

// ---- x_mean = mean_t(x1) ----
__global__ __launch_bounds__(128) void k_mean(const __half* __restrict__ x1h,
                                              float* __restrict__ xmean){
    const int j = threadIdx.x;
    const int b = blockIdx.x;
    const __half* p = x1h + (long)b*TT*DD + j;
    float s = 0.f;
    for(int t=0;t<TT;++t) s += __half2float(p[(long)t*DD]);
    xmean[b*DD + j] = s * (1.0f/TT);
}

// ---- gamma/conf/x_final; writes xch = [xf16 | m16 | d16] per row ----
__global__ __launch_bounds__(128) void k_gate(const __half* __restrict__ x1h,
    const float* __restrict__ xmask, const float* __restrict__ xdelta,
    const float* __restrict__ noise,
    const float* __restrict__ Wd1, const float* __restrict__ bd1,
    const float* __restrict__ Wd2, const float* __restrict__ bd2,
    const float* __restrict__ Wc,  const float* __restrict__ bc,
    const float* __restrict__ xmean, __half* __restrict__ xch){
    __shared__ __align__(16) float ds[8][DD];
    __shared__ __align__(16) float t1s[8][DD];
    __shared__ __align__(16) float xhs[8][DD];
    const int j = threadIdx.x;
    const long row0 = (long)blockIdx.x * 32;
    const int b = (int)(row0 >> 8);
    const float xm = xmean[b*DD + j];
    const float b1 = bd1[j], b2 = bd2[j], bcj = bc[j];
    const float4* Wd1_4 = (const float4*)(Wd1 + j*DD);
    const float4* Wd2_4 = (const float4*)(Wd2 + j*DD);
    const float4* Wc_4  = (const float4*)(Wc  + j*2*DD);
    for(int g=0; g<4; ++g){
        const long rbase = row0 + g*8;
        for(int r=0;r<8;++r)
            ds[r][j] = fminf(fmaxf(xdelta[(rbase+r)*DD + j], 0.f), 100.f);
        __syncthreads();
        float acc[8];
        #pragma unroll
        for(int r=0;r<8;++r) acc[r] = b1;
        for(int k4=0;k4<DD/4;++k4){
            float4 w = Wd1_4[k4];
            #pragma unroll
            for(int r=0;r<8;++r){
                float4 c = ((const float4*)ds[r])[k4];
                acc[r] += c.x*w.x + c.y*w.y + c.z*w.z + c.w*w.w;
            }
        }
        for(int r=0;r<8;++r) t1s[r][j] = fmaxf(acc[r], 0.f);
        __syncthreads();
        #pragma unroll
        for(int r=0;r<8;++r) acc[r] = b2;
        for(int k4=0;k4<DD/4;++k4){
            float4 w = Wd2_4[k4];
            #pragma unroll
            for(int r=0;r<8;++r){
                float4 c = ((const float4*)t1s[r])[k4];
                acc[r] += c.x*w.x + c.y*w.y + c.z*w.z + c.w*w.w;
            }
        }
        for(int r=0;r<8;++r){
            float gmm = sigmoidf_(acc[r]);
            float m  = xmask[(rbase+r)*DD + j];
            float xv = __half2float(x1h[(rbase+r)*DD + j]);
            xhs[r][j] = m*xv + (1.f-m)*gmm*xm;
        }
        __syncthreads();
        #pragma unroll
        for(int r=0;r<8;++r) acc[r] = bcj;
        for(int k4=0;k4<DD/4;++k4){
            float4 w = Wc_4[k4];
            #pragma unroll
            for(int r=0;r<8;++r){
                float4 c = ((const float4*)xhs[r])[k4];
                acc[r] += c.x*w.x + c.y*w.y + c.z*w.z + c.w*w.w;
            }
        }
        for(int k4=0;k4<DD/4;++k4){
            float4 w = Wc_4[DD/4 + k4];
            #pragma unroll
            for(int r=0;r<8;++r){
                float4 c = ((const float4*)ds[r])[k4];
                acc[r] += c.x*w.x + c.y*w.y + c.z*w.z + c.w*w.w;
            }
        }
        for(int r=0;r<8;++r){
            float conf = sigmoidf_(acc[r]);
            float xh = xhs[r][j];
            float nz = noise[(rbase+r)*DD + j];
            float m  = xmask[(rbase+r)*DD + j];
            float xfin = xh*conf + nz*(1.f-conf);
            size_t ro = (size_t)(rbase+r)*384;
            xch[ro + j]       = __float2half(xfin);
            xch[ro + 128 + j] = __float2half(m);
            xch[ro + 256 + j] = __float2half(ds[r][j]);
        }
        __syncthreads();
    }
}

// ---- proj: pxh[row][768] = xch[row][0:384] @ Wcat^T + bcat   (f16 dot2) ----
__global__ __launch_bounds__(256) void k_proj(const __half* __restrict__ xch,
                                              const __half* __restrict__ Wcat,
                                              const float* __restrict__ bcat,
                                              __half* __restrict__ pxh){
    __shared__ __align__(16) uint_t As[64*192];   // 64 rows x 384 f16
    const uint_t* src = (const uint_t*)xch + (size_t)blockIdx.x*64*192;
    for(int i=threadIdx.x; i<64*192; i+=256) As[i] = src[i];
    __syncthreads();
    const int tid = threadIdx.x;
    const int c0 = (tid & 15)*4;
    const int r0 = (tid >> 4)*4;
    const int g  = (tid >> 4) & 3;          // bank-rotation group
    const int ct0 = blockIdx.y*64;
    const uint_t* Wc32 = (const uint_t*)Wcat;
    float acc[4][4] = {};
    for(int kk=0; kk<48; ++kk){
        int kc = kk + g; if(kc >= 48) kc -= 48;
        uint4 a[4], bv[4];
        #pragma unroll
        for(int r=0;r<4;++r) a[r] = *(const uint4*)&As[(r0+r)*192 + kc*4];
        #pragma unroll
        for(int c=0;c<4;++c) bv[c] = *(const uint4*)(Wc32 + (size_t)(ct0+c0+c)*192 + kc*4);
        #pragma unroll
        for(int r=0;r<4;++r){
            #pragma unroll
            for(int c=0;c<4;++c){
                acc[r][c] = d2(a[r].x, bv[c].x, acc[r][c]);
                acc[r][c] = d2(a[r].y, bv[c].y, acc[r][c]);
                acc[r][c] = d2(a[r].z, bv[c].z, acc[r][c]);
                acc[r][c] = d2(a[r].w, bv[c].w, acc[r][c]);
            }
        }
    }
    const size_t row0 = (size_t)blockIdx.x*64 + r0;
    float bb0 = bcat[ct0+c0+0], bb1 = bcat[ct0+c0+1], bb2 = bcat[ct0+c0+2], bb3 = bcat[ct0+c0+3];
    #pragma unroll
    for(int r=0;r<4;++r){
        __half2 p0; p0.x = __float2half(acc[r][0]+bb0); p0.y = __float2half(acc[r][1]+bb1);
        __half2 p1; p1.x = __float2half(acc[r][2]+bb2); p1.y = __float2half(acc[r][3]+bb3);
        __half2* outp = (__half2*)(pxh + (row0+r)*768 + ct0 + c0);
        outp[0] = p0; outp[1] = p1;
    }
}

// ---- GRU recurrence: register-resident f16 weights, 2 rows/block ----
__global__ __launch_bounds__(512,2) void k_gru2(const __half* __restrict__ pxh,
                                                const __half* __restrict__ Wrec,
                                                float* __restrict__ hout){
    __shared__ __align__(16) __half h16[2][256];
    __shared__ __align__(16) __half rh16[2][256];
    __shared__ __align__(16) uint_t pxs[2][768];   // [buf][2 rows x 384 u32]
    const int t  = threadIdx.x;
    const int j  = t >> 1;
    const int kh = t & 1;
    const long b0 = (long)blockIdx.x*2;
    const uint_t* Wr32 = (const uint_t*)Wrec;

    uint_t wz[64], wr[64], wh[64];
    #pragma unroll
    for(int q=0;q<64;++q){
        wz[q] = Wr32[(size_t)(      j)*128 + kh*64 + q];
        wr[q] = Wr32[(size_t)(256 + j)*128 + kh*64 + q];
        wh[q] = Wr32[(size_t)(512 + j)*128 + kh*64 + q];
    }

    const uint_t* px32 = (const uint_t*)pxh;
    auto ldpx = [&](int step, int f)->uint_t{
        int row = (f >= 384); int off = f - row*384;
        return px32[(size_t)((b0+row)*TT + step)*384 + off];
    };

    if(kh==0){ h16[0][j] = __float2half(0.f); h16[1][j] = __float2half(0.f); }
    {   uint_t p0 = ldpx(0, t);
        pxs[0][t] = p0;
        if(t < 256){ uint_t p1 = ldpx(0, t+512); pxs[0][t+512] = p1; }
    }
    float hreg0 = 0.f, hreg1 = 0.f;
    __syncthreads();

    const uint_t* h0p = ((const uint_t*)&h16[0][0]) + kh*64;
    const uint_t* h1p = ((const uint_t*)&h16[1][0]) + kh*64;
    const uint_t* r0p = ((const uint_t*)&rh16[0][0]) + kh*64;
    const uint_t* r1p = ((const uint_t*)&rh16[1][0]) + kh*64;

    for(int s=0; s<TT; ++s){
        const int cur = s & 1;
        uint_t nf0 = 0, nf1 = 0;
        if(s < TT-1){ nf0 = ldpx(s+1, t); if(t < 256) nf1 = ldpx(s+1, t+512); }

        const __half* pxcur = (const __half*)pxs[cur];
        // phase 1: z and r gates
        float az0=0.f, az1=0.f, ar0=0.f, ar1=0.f;
        #pragma unroll
        for(int q=0;q<64;q+=4){
            uint4 hv0 = *(const uint4*)(h0p + q);
            uint4 hv1 = *(const uint4*)(h1p + q);
            az0=d2(wz[q+0],hv0.x,az0); ar0=d2(wr[q+0],hv0.x,ar0); az1=d2(wz[q+0],hv1.x,az1); ar1=d2(wr[q+0],hv1.x,ar1);
            az0=d2(wz[q+1],hv0.y,az0); ar0=d2(wr[q+1],hv0.y,ar0); az1=d2(wz[q+1],hv1.y,az1); ar1=d2(wr[q+1],hv1.y,ar1);
            az0=d2(wz[q+2],hv0.z,az0); ar0=d2(wr[q+2],hv0.z,ar0); az1=d2(wz[q+2],hv1.z,az1); ar1=d2(wr[q+2],hv1.z,ar1);
            az0=d2(wz[q+3],hv0.w,az0); ar0=d2(wr[q+3],hv0.w,ar0); az1=d2(wz[q+3],hv1.w,az1); ar1=d2(wr[q+3],hv1.w,ar1);
        }
        az0 += __shfl_xor(az0,1); az1 += __shfl_xor(az1,1);
        ar0 += __shfl_xor(ar0,1); ar1 += __shfl_xor(ar1,1);
        float z0 = sigmoidf_(__half2float(pxcur[      j]) + az0);
        float z1 = sigmoidf_(__half2float(pxcur[768 + j]) + az1);
        float r0 = sigmoidf_(__half2float(pxcur[256 + j]) + ar0);
        float r1 = sigmoidf_(__half2float(pxcur[768+256+j]) + ar1);
        if(kh==0){
            rh16[0][j] = __float2half(r0*hreg0);
            rh16[1][j] = __float2half(r1*hreg1);
        }
        __syncthreads();
        // phase 2: h_tilde
        float ah0=0.f, ah1=0.f;
        #pragma unroll
        for(int q=0;q<64;q+=4){
            uint4 rv0 = *(const uint4*)(r0p + q);
            uint4 rv1 = *(const uint4*)(r1p + q);
            ah0=d2(wh[q+0],rv0.x,ah0); ah1=d2(wh[q+0],rv1.x,ah1);
            ah0=d2(wh[q+1],rv0.y,ah0); ah1=d2(wh[q+1],rv1.y,ah1);
            ah0=d2(wh[q+2],rv0.z,ah0); ah1=d2(wh[q+2],rv1.z,ah1);
            ah0=d2(wh[q+3],rv0.w,ah0); ah1=d2(wh[q+3],rv1.w,ah1);
        }
        ah0 += __shfl_xor(ah0,1); ah1 += __shfl_xor(ah1,1);
        float ht0 = tanhf_(__half2float(pxcur[512 + j]) + ah0);
        float ht1 = tanhf_(__half2float(pxcur[768+512+j]) + ah1);
        hreg0 = (1.f - z0)*hreg0 + z0*ht0;
        hreg1 = (1.f - z1)*hreg1 + z1*ht1;
        if(kh==0){
            h16[0][j] = __float2half(hreg0);
            h16[1][j] = __float2half(hreg1);
        }
        if(s < TT-1){
            pxs[cur^1][t] = nf0;
            if(t < 256) pxs[cur^1][t+512] = nf1;
        }
        __syncthreads();
    }
    if(kh==0){
        hout[(b0+0)*HH + j] = hreg0;
        hout[(b0+1)*HH + j] = hreg1;
    }
}

// ---- LayerNorm + output projection ----
__global__ __launch_bounds__(256) void k_lnout(const float* __restrict__ hbuf,
    const float* __restrict__ lng, const float* __restrict__ lnb,
    const float* __restrict__ Wo, const float* __restrict__ bo,
    float* __restrict__ out){
    __shared__ __align__(16) float ln_s[HH];
    __shared__ float red[8];
    const int b = blockIdx.x, j = threadIdx.x;
    const float v = hbuf[(long)b*HH + j];
    float s = v, ss = v*v;
    const int lane = j & 63, w = j >> 6;
    for(int off=32; off>0; off>>=1){
        s  += __shfl_down(s,  off);
        ss += __shfl_down(ss, off);
    }
    if(lane == 0){ red[w] = s; red[4+w] = ss; }
    __syncthreads();
    float tot  = red[0]+red[1]+red[2]+red[3];
    float tot2 = red[4]+red[5]+red[6]+red[7];
    float mu  = tot  * (1.0f/HH);
    float var = tot2 * (1.0f/HH) - mu*mu;
    float rstd = rsqrtf(var + 1e-5f);
    ln_s[j] = (v - mu)*rstd*lng[j] + lnb[j];
    __syncthreads();
    if(j < OO){
        float acc = bo[j];
        const float4* w4 = (const float4*)(Wo + j*HH);
        const float4* l4 = (const float4*)ln_s;
        for(int k4=0;k4<HH/4;++k4){
            float4 wv = w4[k4], c = l4[k4];
            acc += wv.x*c.x + wv.y*c.y + wv.z*c.z + wv.w*c.w;
        }
        out[(long)b*OO + j] = acc;
    }
}

// ================= fallback path (round-0, proven, needs ~135MB ws) =================

__global__ __launch_bounds__(128) void k_emb_o(const float* __restrict__ x,
                                               const float* __restrict__ W,
                                               const float* __restrict__ bias,
                                               float* __restrict__ x1){
    __shared__ __align__(16) float xs[8][DD];
    const int j = threadIdx.x;
    const long row0 = (long)blockIdx.x * 32;
    const float bj = bias[j];
    const float4* W4 = (const float4*)(W + j*DD);
    for(int g=0; g<4; ++g){
        const long rbase = row0 + g*8;
        for(int r=0;r<8;++r) xs[r][j] = x[(rbase+r)*DD + j];
        __syncthreads();
        float acc[8];
        #pragma unroll
        for(int r=0;r<8;++r) acc[r] = bj;
        for(int k4=0;k4<DD/4;++k4){
            float4 w = W4[k4];
            #pragma unroll
            for(int r=0;r<8;++r){
                float4 c = ((const float4*)xs[r])[k4];
                acc[r] += c.x*w.x + c.y*w.y + c.z*w.z + c.w*w.w;
            }
        }
        for(int r=0;r<8;++r) x1[(rbase+r)*DD + j] = acc[r];
        __syncthreads();
    }
}

__global__ __launch_bounds__(128) void k_mean_o(const float* __restrict__ x1,
                                                float* __restrict__ xmean){
    const int j = threadIdx.x;
    const int b = blockIdx.x;
    const float* p = x1 + (long)b*TT*DD + j;
    float s = 0.f;
    for(int t=0;t<TT;++t) s += p[(long)t*DD];
    xmean[b*DD + j] = s * (1.0f/TT);
}

__global__ __launch_bounds__(128) void k_gate_o(float* __restrict__ xf,
    const float* __restrict__ xmask, const float* __restrict__ xdelta,
    const float* __restrict__ noise,
    const float* __restrict__ Wd1, const float* __restrict__ bd1,
    const float* __restrict__ Wd2, const float* __restrict__ bd2,
    const float* __restrict__ Wc,  const float* __restrict__ bc,
    const float* __restrict__ xmean){
    __shared__ __align__(16) float ds[8][DD];
    __shared__ __align__(16) float t1s[8][DD];
    __shared__ __align__(16) float xhs[8][DD];
    const int j = threadIdx.x;
    const long row0 = (long)blockIdx.x * 32;
    const int b = (int)(row0 >> 8);
    const float xm = xmean[b*DD + j];
    const float b1 = bd1[j], b2 = bd2[j], bcj = bc[j];
    const float4* Wd1_4 = (const float4*)(Wd1 + j*DD);
    const float4* Wd2_4 = (const float4*)(Wd2 + j*DD);
    const float4* Wc_4  = (const float4*)(Wc  + j*2*DD);
    for(int g=0; g<4; ++g){
        const long rbase = row0 + g*8;
        for(int r=0;r<8;++r)
            ds[r][j] = fminf(fmaxf(xdelta[(rbase+r)*DD + j], 0.f), 100.f);
        __syncthreads();
        float acc[8];
        #pragma unroll
        for(int r=0;r<8;++r) acc[r] = b1;
        for(int k4=0;k4<DD/4;++k4){
            float4 w = Wd1_4[k4];
            #pragma unroll
            for(int r=0;r<8;++r){
                float4 c = ((const float4*)ds[r])[k4];
                acc[r] += c.x*w.x + c.y*w.y + c.z*w.z + c.w*w.w;
            }
        }
        for(int r=0;r<8;++r) t1s[r][j] = fmaxf(acc[r], 0.f);
        __syncthreads();
        #pragma unroll
        for(int r=0;r<8;++r) acc[r] = b2;
        for(int k4=0;k4<DD/4;++k4){
            float4 w = Wd2_4[k4];
            #pragma unroll
            for(int r=0;r<8;++r){
                float4 c = ((const float4*)t1s[r])[k4];
                acc[r] += c.x*w.x + c.y*w.y + c.z*w.z + c.w*w.w;
            }
        }
        for(int r=0;r<8;++r){
            float gmm = sigmoidf_(acc[r]);
            float m  = xmask[(rbase+r)*DD + j];
            float xv = xf[(rbase+r)*DD + j];
            xhs[r][j] = m*xv + (1.f-m)*gmm*xm;
        }
        __syncthreads();
        #pragma unroll
        for(int r=0;r<8;++r) acc[r] = bcj;
        for(int k4=0;k4<DD/4;++k4){
            float4 w = Wc_4[k4];
            #pragma unroll
            for(int r=0;r<8;++r){
                float4 c = ((const float4*)xhs[r])[k4];
                acc[r] += c.x*w.x + c.y*w.y + c.z*w.z + c.w*w.w;
            }
        }
        for(int k4=0;k4<DD/4;++k4){
            float4 w = Wc_4[DD/4 + k4];
            #pragma unroll
            for(int r=0;r<8;++r){
                float4 c = ((const float4*)ds[r])[k4];
                acc[r] += c.x*w.x + c.y*w.y + c.z*w.z + c.w*w.w;
            }
        }
        for(int r=0;r<8;++r){
            float conf = sigmoidf_(acc[r]);
            float xh = xhs[r][j];
            float nz = noise[(rbase+r)*DD + j];
            xf[(rbase+r)*DD + j] = xh*conf + nz*(1.f-conf);
        }
        __syncthreads();
    }
}

__global__ __launch_bounds__(1024) void k_gru_o(const float* __restrict__ xf,
    const float* __restrict__ xmask, const float* __restrict__ xdelta,
    const float* __restrict__ Wz, const float* __restrict__ bz,
    const float* __restrict__ Wr, const float* __restrict__ br,
    const float* __restrict__ Wh, const float* __restrict__ bh,
    float* __restrict__ hout){
    __shared__ __align__(16) float xc[4][KH];
    __shared__ __align__(16) float rh[4][HH];
    const int tid = threadIdx.x;
    const int j  = tid & 255;
    const int bl = tid >> 8;
    const long bbase = (long)blockIdx.x * 4;
    xc[bl][384 + j] = 0.f;
    const float bzj = bz[j], brj = br[j], bhj = bh[j];
    const float4* Wz4 = (const float4*)(Wz + (long)j*KH);
    const float4* Wr4 = (const float4*)(Wr + (long)j*KH);
    const float4* Wh4 = (const float4*)(Wh + (long)j*KH);
    __syncthreads();
    for(int t=0;t<TT;++t){
        if(tid < 4*DD){
            int sb = tid >> 7, k = tid & 127;
            long row = (bbase + sb)*TT + t;
            xc[sb][k]       = xf[row*DD + k];
            xc[sb][128 + k] = xmask[row*DD + k];
            xc[sb][256 + k] = fminf(fmaxf(xdelta[row*DD + k], 0.f), 100.f);
        }
        __syncthreads();
        const float4* cb = (const float4*)xc[bl];
        float az = bzj, ar = brj;
        for(int k4=0;k4<KH/4;++k4){
            float4 wz = Wz4[k4], wrr = Wr4[k4];
            float4 v = cb[k4];
            az += v.x*wz.x + v.y*wz.y + v.z*wz.z + v.w*wz.w;
            ar += v.x*wrr.x + v.y*wrr.y + v.z*wrr.z + v.w*wrr.w;
        }
        float z = sigmoidf_(az);
        float r = sigmoidf_(ar);
        rh[bl][j] = r * xc[bl][384 + j];
        __syncthreads();
        float ah = bhj;
        for(int k4=0;k4<96;++k4){
            float4 wh = Wh4[k4];
            float4 v = cb[k4];
            ah += v.x*wh.x + v.y*wh.y + v.z*wh.z + v.w*wh.w;
        }
        const float4* rp = (const float4*)rh[bl];
        for(int k4=0;k4<64;++k4){
            float4 wh = Wh4[96 + k4];
            float4 v = rp[k4];
            ah += v.x*wh.x + v.y*wh.y + v.z*wh.z + v.w*wh.w;
        }
        float ht = tanhf(ah);
        float hold = xc[bl][384 + j];
        float hn = (1.f - z)*hold + z*ht;
        xc[bl][384 + j] = hn;
        __syncthreads();
    }
    hout[(bbase + bl)*HH + j] = xc[bl][384 + j];
}

// ================= launch =================

extern "C" void kernel_launch(void* const* d_in, const int* in_sizes, int n_in,
                              void* d_out, int out_size, void* d_ws, size_t ws_size,
                              hipStream_t stream){
    const float* x      = (const float*)d_in[0];
    const float* xmask  = (const float*)d_in[1];
    const float* xdelta = (const float*)d_in[2];
    const float* noise  = (const float*)d_in[3];
    const float* W_emb  = (const float*)d_in[4];
    const float* b_emb  = (const float*)d_in[5];
    const float* W_d1   = (const float*)d_in[6];
    const float* b_d1   = (const float*)d_in[7];
    const float* W_d2   = (const float*)d_in[8];
    const float* b_d2   = (const float*)d_in[9];
    const float* W_c    = (const float*)d_in[10];
    const float* b_c    = (const float*)d_in[11];
    const float* W_z    = (const float*)d_in[12];
    const float* b_z    = (const float*)d_in[13];
    const float* W_r    = (const float*)d_in[14];
    const float* b_r    = (const float*)d_in[15];
    const float* W_h    = (const float*)d_in[16];
    const float* b_h    = (const float*)d_in[17];
    const float* ln_g   = (const float*)d_in[18];
    const float* ln_b   = (const float*)d_in[19];
    const float* W_o    = (const float*)d_in[20];
    const float* b_o    = (const float*)d_in[21];
    float* out = (float*)d_out;
    char* ws = (char*)d_ws;

    if(ws_size >= WS_NEED){
        __half* pxh   = (__half*)(ws + OFF_PXH);
        __half* x1h   = (__half*)(ws + OFF_X1H);   // aliases pxh head; dead before proj writes
        __half* xch   = (__half*)(ws + OFF_XCH);
        __half* Wcat  = (__half*)(ws + OFF_WCAT);
        __half* Wrec  = (__half*)(ws + OFF_WREC);
        float*  bcat  = (float*)(ws + OFF_BCAT);
        float*  xmean = (float*)(ws + OFF_XMEAN);
        float*  hbuf  = (float*)(ws + OFF_HBUF);

        k_wprep<<<dim3(768),        dim3(128), 0, stream>>>(W_z,W_r,W_h,b_z,b_r,b_h, Wcat, Wrec, bcat);
        k_emb  <<<dim3(BT/32),      dim3(128), 0, stream>>>(x, W_emb, b_emb, x1h);
        k_mean <<<dim3(BB),         dim3(128), 0, stream>>>(x1h, xmean);
        k_gate <<<dim3(BT/32),      dim3(128), 0, stream>>>(x1h, xmask, xdelta, noise,
                                                            W_d1,b_d1,W_d2,b_d2,W_c,b_c, xmean, xch);
        k_proj <<<dim3(BT/64, 12),  dim3(256), 0, stream>>>(xch, Wcat, bcat, pxh);
        k_gru2 <<<dim3(BB/2),       dim3(512), 0, stream>>>(pxh, Wrec, hbuf);
        k_lnout<<<dim3(BB),         dim3(256), 0, stream>>>(hbuf, ln_g, ln_b, W_o, b_o, out);
    } else {
        float* xf    = (float*)ws;
        float* xmean = (float*)(ws + (size_t)BT*DD*4);
        float* hbuf  = (float*)(ws + (size_t)BT*DD*4 + (size_t)BB*DD*4);
        k_emb_o  <<<dim3(BT/32), dim3(128), 0, stream>>>(x, W_emb, b_emb, xf);
        k_mean_o <<<dim3(BB),    dim3(128), 0, stream>>>(xf, xmean);
        k_gate_o <<<dim3(BT/32), dim3(128), 0, stream>>>(xf, xmask, xdelta, noise,
                                                         W_d1,b_d1,W_d2,b_d2,W_c,b_c, xmean);
        k_gru_o  <<<dim3(BB/4),  dim3(1024),0, stream>>>(xf, xmask, xdelta,
                                                         W_z,b_z,W_r,b_r,W_h,b_h, hbuf);
        k_lnout  <<<dim3(BB),    dim3(256), 0, stream>>>(hbuf, ln_g, ln_b, W_o, b_o, out);
    }
}

// Round 3
// 3766.975 us; speedup vs baseline: 15.6516x; 15.6300x over previous
//
#include <hip/hip_runtime.h>
#include <hip/hip_fp16.h>
#include <math.h>

#define BB 512
#define TT 256
#define DD 128
#define HH 256
#define OO 128
#define KH 640   // 3*D + H
#define BT (BB*TT)

typedef unsigned int uint_t;

__device__ __forceinline__ float sigmoidf_(float x){ return 1.0f/(1.0f+__expf(-x)); }
__device__ __forceinline__ float tanhf_(float x){ float e = __expf(-2.0f*x); return 2.0f/(1.0f+e) - 1.0f; }

// packed-f16 dot2 with f32 accumulator
typedef _Float16 h2v __attribute__((ext_vector_type(2)));
__device__ __forceinline__ float d2(uint_t a, uint_t b, float c){
#if __has_builtin(__builtin_amdgcn_fdot2)
    return __builtin_amdgcn_fdot2(__builtin_bit_cast(h2v, a), __builtin_bit_cast(h2v, b), c, false);
#else
    __half2 ha = __builtin_bit_cast(__half2, a);
    __half2 hb = __builtin_bit_cast(__half2, b);
    return c + __half2float(ha.x)*__half2float(hb.x) + __half2float(ha.y)*__half2float(hb.y);
#endif
}
__device__ __forceinline__ uint_t pack2(float a, float b){
    __half2 h; h.x = __float2half(a); h.y = __float2half(b);
    return __builtin_bit_cast(uint_t, h);
}

// ---- ws layout (chunked; Tc runtime power of 2) ----
// [0)               xfh   : BT*128 f16 = 33,554,432  (x1 then x_final, in place)
// [33554432)        pxc   : 512*Tc*768 f16 = Tc*786,432
// then Wcat 589,824 | Wrec 393,216 | bcat 3,072 | xmean 262,144 | hstate 524,288
static const size_t SZ_XFH  = (size_t)BT*DD*2;
static const size_t TAIL_SZ = 589824 + 393216 + 3072 + 262144 + 524288;

// ---- weight prep: f32 -> f16, split cat(384) / rec(256) ----
__global__ __launch_bounds__(128) void k_wprep(const float* __restrict__ Wz, const float* __restrict__ Wr,
                                               const float* __restrict__ Wh, const float* __restrict__ bz,
                                               const float* __restrict__ br, const float* __restrict__ bh,
                                               __half* __restrict__ Wcat, __half* __restrict__ Wrec,
                                               float* __restrict__ bcat){
    int gj = blockIdx.x; int j = gj & 255;
    const float* src  = (gj < 256 ? Wz : (gj < 512 ? Wr : Wh)) + (size_t)j*KH;
    const float* bsrc = (gj < 256 ? bz : (gj < 512 ? br : bh));
    for(int k=threadIdx.x; k<384; k+=128) Wcat[(size_t)gj*384 + k] = __float2half(src[k]);
    for(int k=threadIdx.x; k<256; k+=128) Wrec[(size_t)gj*256 + k] = __float2half(src[384+k]);
    if(threadIdx.x==0) bcat[gj] = bsrc[j];
}

// ---- x1 = x @ W_emb^T + b  (f16 out) ----
__global__ __launch_bounds__(128) void k_emb(const float* __restrict__ x,
                                             const float* __restrict__ W,
                                             const float* __restrict__ bias,
                                             __half* __restrict__ x1h){
    __shared__ __align__(16) float xs[8][DD];
    const int j = threadIdx.x;
    const long row0 = (long)blockIdx.x * 32;
    const float bj = bias[j];
    const float4* W4 = (const float4*)(W + j*DD);
    for(int g=0; g<4; ++g){
        const long rbase = row0 + g*8;
        for(int r=0;r<8;++r) xs[r][j] = x[(rbase+r)*DD + j];
        __syncthreads();
        float acc[8];
        #pragma unroll
        for(int r=0;r<8;++r) acc[r] = bj;
        for(int k4=0;k4<DD/4;++k4){
            float4 w = W4[k4];
            #pragma unroll
            for(int r=0;r<8;++r){
                float4 c = ((const float4*)xs[r])[k4];
                acc[r] += c.x*w.x + c.y*w.y + c.z*w.z + c.w*w.w;
            }
        }
        for(int r=0;r<8;++r) x1h[(rbase+r)*DD + j] = __float2half(acc[r]);
        __syncthreads();
    }
}

// ---- x_mean = mean_t(x1) ----
__global__ __launch_bounds__(128) void k_mean(const __half* __restrict__ x1h,
                                              float* __restrict__ xmean){
    const int j = threadIdx.x;
    const int b = blockIdx.x;
    const __half* p = x1h + (long)b*TT*DD + j;
    float s = 0.f;
    for(int t=0;t<TT;++t) s += __half2float(p[(long)t*DD]);
    xmean[b*DD + j] = s * (1.0f/TT);
}

// ---- gamma/conf/x_final; in-place f16 on xfh ----
__global__ __launch_bounds__(128) void k_gate(__half* __restrict__ xfh,
    const float* __restrict__ xmask, const float* __restrict__ xdelta,
    const float* __restrict__ noise,
    const float* __restrict__ Wd1, const float* __restrict__ bd1,
    const float* __restrict__ Wd2, const float* __restrict__ bd2,
    const float* __restrict__ Wc,  const float* __restrict__ bc,
    const float* __restrict__ xmean){
    __shared__ __align__(16) float ds[8][DD];
    __shared__ __align__(16) float t1s[8][DD];
    __shared__ __align__(16) float xhs[8][DD];
    const int j = threadIdx.x;
    const long row0 = (long)blockIdx.x * 32;
    const int b = (int)(row0 >> 8);
    const float xm = xmean[b*DD + j];
    const float b1 = bd1[j], b2 = bd2[j], bcj = bc[j];
    const float4* Wd1_4 = (const float4*)(Wd1 + j*DD);
    const float4* Wd2_4 = (const float4*)(Wd2 + j*DD);
    const float4* Wc_4  = (const float4*)(Wc  + j*2*DD);
    for(int g=0; g<4; ++g){
        const long rbase = row0 + g*8;
        for(int r=0;r<8;++r)
            ds[r][j] = fminf(fmaxf(xdelta[(rbase+r)*DD + j], 0.f), 100.f);
        __syncthreads();
        float acc[8];
        #pragma unroll
        for(int r=0;r<8;++r) acc[r] = b1;
        for(int k4=0;k4<DD/4;++k4){
            float4 w = Wd1_4[k4];
            #pragma unroll
            for(int r=0;r<8;++r){
                float4 c = ((const float4*)ds[r])[k4];
                acc[r] += c.x*w.x + c.y*w.y + c.z*w.z + c.w*w.w;
            }
        }
        for(int r=0;r<8;++r) t1s[r][j] = fmaxf(acc[r], 0.f);
        __syncthreads();
        #pragma unroll
        for(int r=0;r<8;++r) acc[r] = b2;
        for(int k4=0;k4<DD/4;++k4){
            float4 w = Wd2_4[k4];
            #pragma unroll
            for(int r=0;r<8;++r){
                float4 c = ((const float4*)t1s[r])[k4];
                acc[r] += c.x*w.x + c.y*w.y + c.z*w.z + c.w*w.w;
            }
        }
        for(int r=0;r<8;++r){
            float gmm = sigmoidf_(acc[r]);
            float m  = xmask[(rbase+r)*DD + j];
            float xv = __half2float(xfh[(rbase+r)*DD + j]);
            xhs[r][j] = m*xv + (1.f-m)*gmm*xm;
        }
        __syncthreads();
        #pragma unroll
        for(int r=0;r<8;++r) acc[r] = bcj;
        for(int k4=0;k4<DD/4;++k4){
            float4 w = Wc_4[k4];
            #pragma unroll
            for(int r=0;r<8;++r){
                float4 c = ((const float4*)xhs[r])[k4];
                acc[r] += c.x*w.x + c.y*w.y + c.z*w.z + c.w*w.w;
            }
        }
        for(int k4=0;k4<DD/4;++k4){
            float4 w = Wc_4[DD/4 + k4];
            #pragma unroll
            for(int r=0;r<8;++r){
                float4 c = ((const float4*)ds[r])[k4];
                acc[r] += c.x*w.x + c.y*w.y + c.z*w.z + c.w*w.w;
            }
        }
        for(int r=0;r<8;++r){
            float conf = sigmoidf_(acc[r]);
            float xh = xhs[r][j];
            float nz = noise[(rbase+r)*DD + j];
            xfh[(rbase+r)*DD + j] = __float2half(xh*conf + nz*(1.f-conf));
        }
        __syncthreads();
    }
}

// ---- chunked proj: pxc[b][tl][768] = xc(b,t0+tl) @ Wcat^T + bcat ----
__global__ __launch_bounds__(256) void k_projc(const __half* __restrict__ xfh,
                                               const float* __restrict__ xmask,
                                               const float* __restrict__ xdelta,
                                               const __half* __restrict__ Wcat,
                                               const float* __restrict__ bcat,
                                               __half* __restrict__ pxc,
                                               int t0, int lTc){
    __shared__ __align__(16) uint_t As[64*192];   // 64 rows x 384 f16
    const int tid = threadIdx.x;
    const int rblk = blockIdx.x*64;
    const int mTc = (1<<lTc) - 1;
    const uint_t* xf32 = (const uint_t*)xfh;
    for(int i=tid; i<64*192; i+=256){
        int row = i/192, e = i - row*192;
        int r = rblk + row;
        int b = r >> lTc, tl = r & mTc;
        long srow = (long)b*TT + t0 + tl;
        uint_t v;
        if(e < 64){
            v = xf32[srow*64 + e];
        } else if(e < 128){
            int k = (e-64)*2;
            v = pack2(xmask[srow*DD + k], xmask[srow*DD + k + 1]);
        } else {
            int k = (e-128)*2;
            float f0 = fminf(fmaxf(xdelta[srow*DD + k],     0.f), 100.f);
            float f1 = fminf(fmaxf(xdelta[srow*DD + k + 1], 0.f), 100.f);
            v = pack2(f0, f1);
        }
        As[i] = v;
    }
    __syncthreads();
    const int c0 = (tid & 15)*4;
    const int r0 = (tid >> 4)*4;
    const int g  = (tid >> 4) & 3;
    const int ct0 = blockIdx.y*64;
    const uint_t* Wc32 = (const uint_t*)Wcat;
    float acc[4][4] = {};
    for(int kk=0; kk<48; ++kk){
        int kc = kk + g; if(kc >= 48) kc -= 48;
        uint4 a[4], bv[4];
        #pragma unroll
        for(int r=0;r<4;++r) a[r] = *(const uint4*)&As[(r0+r)*192 + kc*4];
        #pragma unroll
        for(int c=0;c<4;++c) bv[c] = *(const uint4*)(Wc32 + (size_t)(ct0+c0+c)*192 + kc*4);
        #pragma unroll
        for(int r=0;r<4;++r){
            #pragma unroll
            for(int c=0;c<4;++c){
                acc[r][c] = d2(a[r].x, bv[c].x, acc[r][c]);
                acc[r][c] = d2(a[r].y, bv[c].y, acc[r][c]);
                acc[r][c] = d2(a[r].z, bv[c].z, acc[r][c]);
                acc[r][c] = d2(a[r].w, bv[c].w, acc[r][c]);
            }
        }
    }
    const size_t row0 = (size_t)rblk + r0;
    float bb0 = bcat[ct0+c0+0], bb1 = bcat[ct0+c0+1], bb2 = bcat[ct0+c0+2], bb3 = bcat[ct0+c0+3];
    #pragma unroll
    for(int r=0;r<4;++r){
        uint2 pv;
        pv.x = pack2(acc[r][0]+bb0, acc[r][1]+bb1);
        pv.y = pack2(acc[r][2]+bb2, acc[r][3]+bb3);
        *(uint2*)(pxc + (row0+r)*768 + ct0 + c0) = pv;
    }
}

// ---- chunked GRU: register-resident f16 recurrent weights, 2 rows/block ----
__global__ __launch_bounds__(512,2) void k_gruc(const __half* __restrict__ pxc,
                                                const __half* __restrict__ Wrec,
                                                float* __restrict__ hstate,
                                                int Tc, int init){
    __shared__ __align__(16) __half h16[2][256];
    __shared__ __align__(16) __half rh16[2][256];
    __shared__ __align__(16) uint_t pxs[2][768];
    const int t  = threadIdx.x;
    const int j  = t >> 1;
    const int kh = t & 1;
    const long b0 = (long)blockIdx.x*2;
    const uint_t* Wr32 = (const uint_t*)Wrec;

    uint_t wz[64], wr[64], wh[64];
    #pragma unroll
    for(int q=0;q<64;++q){
        wz[q] = Wr32[(size_t)(      j)*128 + kh*64 + q];
        wr[q] = Wr32[(size_t)(256 + j)*128 + kh*64 + q];
        wh[q] = Wr32[(size_t)(512 + j)*128 + kh*64 + q];
    }

    const uint_t* px32 = (const uint_t*)pxc;
    auto ldpx = [&](int tl, int f)->uint_t{
        int row = (f >= 384); int off = f - row*384;
        return px32[((size_t)(b0+row)*Tc + tl)*384 + off];
    };

    float hreg0, hreg1;
    if(init){ hreg0 = 0.f; hreg1 = 0.f; }
    else    { hreg0 = hstate[(b0+0)*HH + j]; hreg1 = hstate[(b0+1)*HH + j]; }
    if(kh==0){ h16[0][j] = __float2half(hreg0); h16[1][j] = __float2half(hreg1); }
    pxs[0][t] = ldpx(0, t);
    if(t < 256) pxs[0][t+512] = ldpx(0, t+512);
    __syncthreads();

    const uint_t* h0p = ((const uint_t*)&h16[0][0]) + kh*64;
    const uint_t* h1p = ((const uint_t*)&h16[1][0]) + kh*64;
    const uint_t* r0p = ((const uint_t*)&rh16[0][0]) + kh*64;
    const uint_t* r1p = ((const uint_t*)&rh16[1][0]) + kh*64;

    for(int s=0; s<Tc; ++s){
        const int cur = s & 1;
        uint_t nf0 = 0, nf1 = 0;
        if(s < Tc-1){ nf0 = ldpx(s+1, t); if(t < 256) nf1 = ldpx(s+1, t+512); }

        const __half* pxcur = (const __half*)pxs[cur];
        // phase 1: z and r gates
        float az0=0.f, az1=0.f, ar0=0.f, ar1=0.f;
        #pragma unroll
        for(int q=0;q<64;q+=4){
            uint4 hv0 = *(const uint4*)(h0p + q);
            uint4 hv1 = *(const uint4*)(h1p + q);
            az0=d2(wz[q+0],hv0.x,az0); ar0=d2(wr[q+0],hv0.x,ar0); az1=d2(wz[q+0],hv1.x,az1); ar1=d2(wr[q+0],hv1.x,ar1);
            az0=d2(wz[q+1],hv0.y,az0); ar0=d2(wr[q+1],hv0.y,ar0); az1=d2(wz[q+1],hv1.y,az1); ar1=d2(wr[q+1],hv1.y,ar1);
            az0=d2(wz[q+2],hv0.z,az0); ar0=d2(wr[q+2],hv0.z,ar0); az1=d2(wz[q+2],hv1.z,az1); ar1=d2(wr[q+2],hv1.z,ar1);
            az0=d2(wz[q+3],hv0.w,az0); ar0=d2(wr[q+3],hv0.w,ar0); az1=d2(wz[q+3],hv1.w,az1); ar1=d2(wr[q+3],hv1.w,ar1);
        }
        az0 += __shfl_xor(az0,1); az1 += __shfl_xor(az1,1);
        ar0 += __shfl_xor(ar0,1); ar1 += __shfl_xor(ar1,1);
        float z0 = sigmoidf_(__half2float(pxcur[        j]) + az0);
        float z1 = sigmoidf_(__half2float(pxcur[768   + j]) + az1);
        float r0 = sigmoidf_(__half2float(pxcur[256   + j]) + ar0);
        float r1 = sigmoidf_(__half2float(pxcur[768+256+j]) + ar1);
        if(kh==0){
            rh16[0][j] = __float2half(r0*hreg0);
            rh16[1][j] = __float2half(r1*hreg1);
        }
        __syncthreads();
        // phase 2: h_tilde
        float ah0=0.f, ah1=0.f;
        #pragma unroll
        for(int q=0;q<64;q+=4){
            uint4 rv0 = *(const uint4*)(r0p + q);
            uint4 rv1 = *(const uint4*)(r1p + q);
            ah0=d2(wh[q+0],rv0.x,ah0); ah1=d2(wh[q+0],rv1.x,ah1);
            ah0=d2(wh[q+1],rv0.y,ah0); ah1=d2(wh[q+1],rv1.y,ah1);
            ah0=d2(wh[q+2],rv0.z,ah0); ah1=d2(wh[q+2],rv1.z,ah1);
            ah0=d2(wh[q+3],rv0.w,ah0); ah1=d2(wh[q+3],rv1.w,ah1);
        }
        ah0 += __shfl_xor(ah0,1); ah1 += __shfl_xor(ah1,1);
        float ht0 = tanhf_(__half2float(pxcur[512    + j]) + ah0);
        float ht1 = tanhf_(__half2float(pxcur[768+512+j]) + ah1);
        hreg0 = (1.f - z0)*hreg0 + z0*ht0;
        hreg1 = (1.f - z1)*hreg1 + z1*ht1;
        if(kh==0){
            h16[0][j] = __float2half(hreg0);
            h16[1][j] = __float2half(hreg1);
        }
        if(s < Tc-1){
            pxs[cur^1][t] = nf0;
            if(t < 256) pxs[cur^1][t+512] = nf1;
        }
        __syncthreads();
    }
    if(kh==0){
        hstate[(b0+0)*HH + j] = hreg0;
        hstate[(b0+1)*HH + j] = hreg1;
    }
}

// ---- LayerNorm + output projection ----
__global__ __launch_bounds__(256) void k_lnout(const float* __restrict__ hbuf,
    const float* __restrict__ lng, const float* __restrict__ lnb,
    const float* __restrict__ Wo, const float* __restrict__ bo,
    float* __restrict__ out){
    __shared__ __align__(16) float ln_s[HH];
    __shared__ float red[8];
    const int b = blockIdx.x, j = threadIdx.x;
    const float v = hbuf[(long)b*HH + j];
    float s = v, ss = v*v;
    const int lane = j & 63, w = j >> 6;
    for(int off=32; off>0; off>>=1){
        s  += __shfl_down(s,  off);
        ss += __shfl_down(ss, off);
    }
    if(lane == 0){ red[w] = s; red[4+w] = ss; }
    __syncthreads();
    float tot  = red[0]+red[1]+red[2]+red[3];
    float tot2 = red[4]+red[5]+red[6]+red[7];
    float mu  = tot  * (1.0f/HH);
    float var = tot2 * (1.0f/HH) - mu*mu;
    float rstd = rsqrtf(var + 1e-5f);
    ln_s[j] = (v - mu)*rstd*lng[j] + lnb[j];
    __syncthreads();
    if(j < OO){
        float acc = bo[j];
        const float4* w4 = (const float4*)(Wo + j*HH);
        const float4* l4 = (const float4*)ln_s;
        for(int k4=0;k4<HH/4;++k4){
            float4 wv = w4[k4], c = l4[k4];
            acc += wv.x*c.x + wv.y*c.y + wv.z*c.z + wv.w*c.w;
        }
        out[(long)b*OO + j] = acc;
    }
}

// ================= fallback path (round-0, proven, ~68MB ws) =================

__global__ __launch_bounds__(128) void k_emb_o(const float* __restrict__ x,
                                               const float* __restrict__ W,
                                               const float* __restrict__ bias,
                                               float* __restrict__ x1){
    __shared__ __align__(16) float xs[8][DD];
    const int j = threadIdx.x;
    const long row0 = (long)blockIdx.x * 32;
    const float bj = bias[j];
    const float4* W4 = (const float4*)(W + j*DD);
    for(int g=0; g<4; ++g){
        const long rbase = row0 + g*8;
        for(int r=0;r<8;++r) xs[r][j] = x[(rbase+r)*DD + j];
        __syncthreads();
        float acc[8];
        #pragma unroll
        for(int r=0;r<8;++r) acc[r] = bj;
        for(int k4=0;k4<DD/4;++k4){
            float4 w = W4[k4];
            #pragma unroll
            for(int r=0;r<8;++r){
                float4 c = ((const float4*)xs[r])[k4];
                acc[r] += c.x*w.x + c.y*w.y + c.z*w.z + c.w*w.w;
            }
        }
        for(int r=0;r<8;++r) x1[(rbase+r)*DD + j] = acc[r];
        __syncthreads();
    }
}

__global__ __launch_bounds__(128) void k_mean_o(const float* __restrict__ x1,
                                                float* __restrict__ xmean){
    const int j = threadIdx.x;
    const int b = blockIdx.x;
    const float* p = x1 + (long)b*TT*DD + j;
    float s = 0.f;
    for(int t=0;t<TT;++t) s += p[(long)t*DD];
    xmean[b*DD + j] = s * (1.0f/TT);
}

__global__ __launch_bounds__(128) void k_gate_o(float* __restrict__ xf,
    const float* __restrict__ xmask, const float* __restrict__ xdelta,
    const float* __restrict__ noise,
    const float* __restrict__ Wd1, const float* __restrict__ bd1,
    const float* __restrict__ Wd2, const float* __restrict__ bd2,
    const float* __restrict__ Wc,  const float* __restrict__ bc,
    const float* __restrict__ xmean){
    __shared__ __align__(16) float ds[8][DD];
    __shared__ __align__(16) float t1s[8][DD];
    __shared__ __align__(16) float xhs[8][DD];
    const int j = threadIdx.x;
    const long row0 = (long)blockIdx.x * 32;
    const int b = (int)(row0 >> 8);
    const float xm = xmean[b*DD + j];
    const float b1 = bd1[j], b2 = bd2[j], bcj = bc[j];
    const float4* Wd1_4 = (const float4*)(Wd1 + j*DD);
    const float4* Wd2_4 = (const float4*)(Wd2 + j*DD);
    const float4* Wc_4  = (const float4*)(Wc  + j*2*DD);
    for(int g=0; g<4; ++g){
        const long rbase = row0 + g*8;
        for(int r=0;r<8;++r)
            ds[r][j] = fminf(fmaxf(xdelta[(rbase+r)*DD + j], 0.f), 100.f);
        __syncthreads();
        float acc[8];
        #pragma unroll
        for(int r=0;r<8;++r) acc[r] = b1;
        for(int k4=0;k4<DD/4;++k4){
            float4 w = Wd1_4[k4];
            #pragma unroll
            for(int r=0;r<8;++r){
                float4 c = ((const float4*)ds[r])[k4];
                acc[r] += c.x*w.x + c.y*w.y + c.z*w.z + c.w*w.w;
            }
        }
        for(int r=0;r<8;++r) t1s[r][j] = fmaxf(acc[r], 0.f);
        __syncthreads();
        #pragma unroll
        for(int r=0;r<8;++r) acc[r] = b2;
        for(int k4=0;k4<DD/4;++k4){
            float4 w = Wd2_4[k4];
            #pragma unroll
            for(int r=0;r<8;++r){
                float4 c = ((const float4*)t1s[r])[k4];
                acc[r] += c.x*w.x + c.y*w.y + c.z*w.z + c.w*w.w;
            }
        }
        for(int r=0;r<8;++r){
            float gmm = sigmoidf_(acc[r]);
            float m  = xmask[(rbase+r)*DD + j];
            float xv = xf[(rbase+r)*DD + j];
            xhs[r][j] = m*xv + (1.f-m)*gmm*xm;
        }
        __syncthreads();
        #pragma unroll
        for(int r=0;r<8;++r) acc[r] = bcj;
        for(int k4=0;k4<DD/4;++k4){
            float4 w = Wc_4[k4];
            #pragma unroll
            for(int r=0;r<8;++r){
                float4 c = ((const float4*)xhs[r])[k4];
                acc[r] += c.x*w.x + c.y*w.y + c.z*w.z + c.w*w.w;
            }
        }
        for(int k4=0;k4<DD/4;++k4){
            float4 w = Wc_4[DD/4 + k4];
            #pragma unroll
            for(int r=0;r<8;++r){
                float4 c = ((const float4*)ds[r])[k4];
                acc[r] += c.x*w.x + c.y*w.y + c.z*w.z + c.w*w.w;
            }
        }
        for(int r=0;r<8;++r){
            float conf = sigmoidf_(acc[r]);
            float xh = xhs[r][j];
            float nz = noise[(rbase+r)*DD + j];
            xf[(rbase+r)*DD + j] = xh*conf + nz*(1.f-conf);
        }
        __syncthreads();
    }
}

__global__ __launch_bounds__(1024) void k_gru_o(const float* __restrict__ xf,
    const float* __restrict__ xmask, const float* __restrict__ xdelta,
    const float* __restrict__ Wz, const float* __restrict__ bz,
    const float* __restrict__ Wr, const float* __restrict__ br,
    const float* __restrict__ Wh, const float* __restrict__ bh,
    float* __restrict__ hout){
    __shared__ __align__(16) float xc[4][KH];
    __shared__ __align__(16) float rh[4][HH];
    const int tid = threadIdx.x;
    const int j  = tid & 255;
    const int bl = tid >> 8;
    const long bbase = (long)blockIdx.x * 4;
    xc[bl][384 + j] = 0.f;
    const float bzj = bz[j], brj = br[j], bhj = bh[j];
    const float4* Wz4 = (const float4*)(Wz + (long)j*KH);
    const float4* Wr4 = (const float4*)(Wr + (long)j*KH);
    const float4* Wh4 = (const float4*)(Wh + (long)j*KH);
    __syncthreads();
    for(int t=0;t<TT;++t){
        if(tid < 4*DD){
            int sb = tid >> 7, k = tid & 127;
            long row = (bbase + sb)*TT + t;
            xc[sb][k]       = xf[row*DD + k];
            xc[sb][128 + k] = xmask[row*DD + k];
            xc[sb][256 + k] = fminf(fmaxf(xdelta[row*DD + k], 0.f), 100.f);
        }
        __syncthreads();
        const float4* cb = (const float4*)xc[bl];
        float az = bzj, ar = brj;
        for(int k4=0;k4<KH/4;++k4){
            float4 wz = Wz4[k4], wrr = Wr4[k4];
            float4 v = cb[k4];
            az += v.x*wz.x + v.y*wz.y + v.z*wz.z + v.w*wz.w;
            ar += v.x*wrr.x + v.y*wrr.y + v.z*wrr.z + v.w*wrr.w;
        }
        float z = sigmoidf_(az);
        float r = sigmoidf_(ar);
        rh[bl][j] = r * xc[bl][384 + j];
        __syncthreads();
        float ah = bhj;
        for(int k4=0;k4<96;++k4){
            float4 wh = Wh4[k4];
            float4 v = cb[k4];
            ah += v.x*wh.x + v.y*wh.y + v.z*wh.z + v.w*wh.w;
        }
        const float4* rp = (const float4*)rh[bl];
        for(int k4=0;k4<64;++k4){
            float4 wh = Wh4[96 + k4];
            float4 v = rp[k4];
            ah += v.x*wh.x + v.y*wh.y + v.z*wh.z + v.w*wh.w;
        }
        float ht = tanhf(ah);
        float hold = xc[bl][384 + j];
        float hn = (1.f - z)*hold + z*ht;
        xc[bl][384 + j] = hn;
        __syncthreads();
    }
    hout[(bbase + bl)*HH + j] = xc[bl][384 + j];
}

// ================= launch =================

extern "C" void kernel_launch(void* const* d_in, const int* in_sizes, int n_in,
                              void* d_out, int out_size, void* d_ws, size_t ws_size,
                              hipStream_t stream){
    const float* x      = (const float*)d_in[0];
    const float* xmask  = (const float*)d_in[1];
    const float* xdelta = (const float*)d_in[2];
    const float* noise  = (const float*)d_in[3];
    const float* W_emb  = (const float*)d_in[4];
    const float* b_emb  = (const float*)d_in[5];
    const float* W_d1   = (const float*)d_in[6];
    const float* b_d1   = (const float*)d_in[7];
    const float* W_d2   = (const float*)d_in[8];
    const float* b_d2   = (const float*)d_in[9];
    const float* W_c    = (const float*)d_in[10];
    const float* b_c    = (const float*)d_in[11];
    const float* W_z    = (const float*)d_in[12];
    const float* b_z    = (const float*)d_in[13];
    const float* W_r    = (const float*)d_in[14];
    const float* b_r    = (const float*)d_in[15];
    const float* W_h    = (const float*)d_in[16];
    const float* b_h    = (const float*)d_in[17];
    const float* ln_g   = (const float*)d_in[18];
    const float* ln_b   = (const float*)d_in[19];
    const float* W_o    = (const float*)d_in[20];
    const float* b_o    = (const float*)d_in[21];
    float* out = (float*)d_out;
    char* ws = (char*)d_ws;

    // pick largest power-of-2 time-chunk that fits
    int Tc = 0, lTc = 0;
    {
        const int cand[4] = {256, 128, 64, 32};
        const int lcand[4] = {8, 7, 6, 5};
        for(int i=0;i<4;++i){
            size_t need = SZ_XFH + (size_t)cand[i]*786432 + TAIL_SZ;
            if(ws_size >= need){ Tc = cand[i]; lTc = lcand[i]; break; }
        }
    }

    if(Tc > 0){
        __half* xfh   = (__half*)(ws);
        char*   p     = ws + SZ_XFH;
        __half* pxc   = (__half*)p;              p += (size_t)Tc*786432;
        __half* Wcat  = (__half*)p;              p += 589824;
        __half* Wrec  = (__half*)p;              p += 393216;
        float*  bcat  = (float*)p;               p += 3072;
        float*  xmean = (float*)p;               p += 262144;
        float*  hstate= (float*)p;

        k_wprep<<<dim3(768),   dim3(128), 0, stream>>>(W_z,W_r,W_h,b_z,b_r,b_h, Wcat, Wrec, bcat);
        k_emb  <<<dim3(BT/32), dim3(128), 0, stream>>>(x, W_emb, b_emb, xfh);
        k_mean <<<dim3(BB),    dim3(128), 0, stream>>>(xfh, xmean);
        k_gate <<<dim3(BT/32), dim3(128), 0, stream>>>(xfh, xmask, xdelta, noise,
                                                       W_d1,b_d1,W_d2,b_d2,W_c,b_c, xmean);
        const int nchunk = TT / Tc;
        for(int c=0; c<nchunk; ++c){
            k_projc<<<dim3(BB*Tc/64, 12), dim3(256), 0, stream>>>(xfh, xmask, xdelta,
                                                                  Wcat, bcat, pxc, c*Tc, lTc);
            k_gruc <<<dim3(BB/2), dim3(512), 0, stream>>>(pxc, Wrec, hstate, Tc, c==0 ? 1 : 0);
        }
        k_lnout<<<dim3(BB), dim3(256), 0, stream>>>(hstate, ln_g, ln_b, W_o, b_o, out);
    } else {
        float* xf    = (float*)ws;
        float* xmean = (float*)(ws + (size_t)BT*DD*4);
        float* hbuf  = (float*)(ws + (size_t)BT*DD*4 + (size_t)BB*DD*4);
        k_emb_o  <<<dim3(BT/32), dim3(128), 0, stream>>>(x, W_emb, b_emb, xf);
        k_mean_o <<<dim3(BB),    dim3(128), 0, stream>>>(xf, xmean);
        k_gate_o <<<dim3(BT/32), dim3(128), 0, stream>>>(xf, xmask, xdelta, noise,
                                                         W_d1,b_d1,W_d2,b_d2,W_c,b_c, xmean);
        k_gru_o  <<<dim3(BB/4),  dim3(1024),0, stream>>>(xf, xmask, xdelta,
                                                         W_z,b_z,W_r,b_r,W_h,b_h, hbuf);
        k_lnout  <<<dim3(BB),    dim3(256), 0, stream>>>(hbuf, ln_g, ln_b, W_o, b_o, out);
    }
}

// Round 4
// 1920.680 us; speedup vs baseline: 30.6970x; 1.9613x over previous
//
#include <hip/hip_runtime.h>
#include <hip/hip_fp16.h>
#include <math.h>

#define BB 512
#define TT 256
#define DD 128
#define HH 256
#define OO 128
#define KH 640   // 3*D + H
#define BT (BB*TT)

typedef unsigned int uint_t;
typedef _Float16 f16x8 __attribute__((ext_vector_type(8)));
typedef float f32x4 __attribute__((ext_vector_type(4)));

__device__ __forceinline__ float sigmoidf_(float x){ return 1.0f/(1.0f+__expf(-x)); }
__device__ __forceinline__ float tanhf_(float x){ float e = __expf(-2.0f*x); return 2.0f/(1.0f+e) - 1.0f; }

// packed-f16 dot2 with f32 accumulator
typedef _Float16 h2v __attribute__((ext_vector_type(2)));
__device__ __forceinline__ float d2(uint_t a, uint_t b, float c){
#if __has_builtin(__builtin_amdgcn_fdot2)
    return __builtin_amdgcn_fdot2(__builtin_bit_cast(h2v, a), __builtin_bit_cast(h2v, b), c, false);
#else
    __half2 ha = __builtin_bit_cast(__half2, a);
    __half2 hb = __builtin_bit_cast(__half2, b);
    return c + __half2float(ha.x)*__half2float(hb.x) + __half2float(ha.y)*__half2float(hb.y);
#endif
}

// ---- ws layout (MFMA path) ----
// xc  : BT*384 f16 = 100,663,296   rows [x_final(128) | mask(128) | delta(128)]
// px  : 512*Tc*768 f16 = Tc*786,432
// Wcat 589,824 | Wrec 393,216 | bcat 3,072 | xmean 262,144 | hstate 524,288
static const size_t SZ_XC   = (size_t)BT*384*2;
static const size_t TAIL_SZ = 589824 + 393216 + 3072 + 262144 + 524288;

// ---- weight prep: f32 -> f16, split cat(384) / rec(256) ----
__global__ __launch_bounds__(128) void k_wprep(const float* __restrict__ Wz, const float* __restrict__ Wr,
                                               const float* __restrict__ Wh, const float* __restrict__ bz,
                                               const float* __restrict__ br, const float* __restrict__ bh,
                                               __half* __restrict__ Wcat, __half* __restrict__ Wrec,
                                               float* __restrict__ bcat){
    int gj = blockIdx.x; int j = gj & 255;
    const float* src  = (gj < 256 ? Wz : (gj < 512 ? Wr : Wh)) + (size_t)j*KH;
    const float* bsrc = (gj < 256 ? bz : (gj < 512 ? br : bh));
    for(int k=threadIdx.x; k<384; k+=128) Wcat[(size_t)gj*384 + k] = __float2half(src[k]);
    for(int k=threadIdx.x; k<256; k+=128) Wrec[(size_t)gj*256 + k] = __float2half(src[384+k]);
    if(threadIdx.x==0) bcat[gj] = bsrc[j];
}

// ---- x1 = x @ W_emb^T + b ; f16 into xc[row][0:128] (stride 384) ----
__global__ __launch_bounds__(128) void k_emb(const float* __restrict__ x,
                                             const float* __restrict__ W,
                                             const float* __restrict__ bias,
                                             __half* __restrict__ xc){
    __shared__ __align__(16) float xs[8][DD];
    const int j = threadIdx.x;
    const long row0 = (long)blockIdx.x * 32;
    const float bj = bias[j];
    const float4* W4 = (const float4*)(W + j*DD);
    for(int g=0; g<4; ++g){
        const long rbase = row0 + g*8;
        for(int r=0;r<8;++r) xs[r][j] = x[(rbase+r)*DD + j];
        __syncthreads();
        float acc[8];
        #pragma unroll
        for(int r=0;r<8;++r) acc[r] = bj;
        for(int k4=0;k4<DD/4;++k4){
            float4 w = W4[k4];
            #pragma unroll
            for(int r=0;r<8;++r){
                float4 c = ((const float4*)xs[r])[k4];
                acc[r] += c.x*w.x + c.y*w.y + c.z*w.z + c.w*w.w;
            }
        }
        for(int r=0;r<8;++r) xc[(rbase+r)*384 + j] = __float2half(acc[r]);
        __syncthreads();
    }
}

// ---- x_mean = mean_t(x1) (x1 lives at xc stride 384) ----
__global__ __launch_bounds__(128) void k_mean(const __half* __restrict__ xc,
                                              float* __restrict__ xmean){
    const int j = threadIdx.x;
    const int b = blockIdx.x;
    const __half* p = xc + (size_t)b*TT*384 + j;
    float s = 0.f;
    for(int t=0;t<TT;++t) s += __half2float(p[(size_t)t*384]);
    xmean[b*DD + j] = s * (1.0f/TT);
}

// ---- gamma/conf/x_final; fills xc row = [x_final | mask | delta] f16 ----
__global__ __launch_bounds__(128) void k_gate(__half* __restrict__ xc,
    const float* __restrict__ xmask, const float* __restrict__ xdelta,
    const float* __restrict__ noise,
    const float* __restrict__ Wd1, const float* __restrict__ bd1,
    const float* __restrict__ Wd2, const float* __restrict__ bd2,
    const float* __restrict__ Wc,  const float* __restrict__ bc,
    const float* __restrict__ xmean){
    __shared__ __align__(16) float ds[8][DD];
    __shared__ __align__(16) float t1s[8][DD];
    __shared__ __align__(16) float xhs[8][DD];
    const int j = threadIdx.x;
    const long row0 = (long)blockIdx.x * 32;
    const int b = (int)(row0 >> 8);
    const float xm = xmean[b*DD + j];
    const float b1 = bd1[j], b2 = bd2[j], bcj = bc[j];
    const float4* Wd1_4 = (const float4*)(Wd1 + j*DD);
    const float4* Wd2_4 = (const float4*)(Wd2 + j*DD);
    const float4* Wc_4  = (const float4*)(Wc  + j*2*DD);
    for(int g=0; g<4; ++g){
        const long rbase = row0 + g*8;
        for(int r=0;r<8;++r)
            ds[r][j] = fminf(fmaxf(xdelta[(rbase+r)*DD + j], 0.f), 100.f);
        __syncthreads();
        float acc[8];
        #pragma unroll
        for(int r=0;r<8;++r) acc[r] = b1;
        for(int k4=0;k4<DD/4;++k4){
            float4 w = Wd1_4[k4];
            #pragma unroll
            for(int r=0;r<8;++r){
                float4 c = ((const float4*)ds[r])[k4];
                acc[r] += c.x*w.x + c.y*w.y + c.z*w.z + c.w*w.w;
            }
        }
        for(int r=0;r<8;++r) t1s[r][j] = fmaxf(acc[r], 0.f);
        __syncthreads();
        #pragma unroll
        for(int r=0;r<8;++r) acc[r] = b2;
        for(int k4=0;k4<DD/4;++k4){
            float4 w = Wd2_4[k4];
            #pragma unroll
            for(int r=0;r<8;++r){
                float4 c = ((const float4*)t1s[r])[k4];
                acc[r] += c.x*w.x + c.y*w.y + c.z*w.z + c.w*w.w;
            }
        }
        for(int r=0;r<8;++r){
            float gmm = sigmoidf_(acc[r]);
            float m  = xmask[(rbase+r)*DD + j];
            float xv = __half2float(xc[(rbase+r)*384 + j]);
            xhs[r][j] = m*xv + (1.f-m)*gmm*xm;
        }
        __syncthreads();
        #pragma unroll
        for(int r=0;r<8;++r) acc[r] = bcj;
        for(int k4=0;k4<DD/4;++k4){
            float4 w = Wc_4[k4];
            #pragma unroll
            for(int r=0;r<8;++r){
                float4 c = ((const float4*)xhs[r])[k4];
                acc[r] += c.x*w.x + c.y*w.y + c.z*w.z + c.w*w.w;
            }
        }
        for(int k4=0;k4<DD/4;++k4){
            float4 w = Wc_4[DD/4 + k4];
            #pragma unroll
            for(int r=0;r<8;++r){
                float4 c = ((const float4*)ds[r])[k4];
                acc[r] += c.x*w.x + c.y*w.y + c.z*w.z + c.w*w.w;
            }
        }
        for(int r=0;r<8;++r){
            float conf = sigmoidf_(acc[r]);
            float xh = xhs[r][j];
            float nz = noise[(rbase+r)*DD + j];
            float m  = xmask[(rbase+r)*DD + j];
            size_t ro = (size_t)(rbase+r)*384;
            xc[ro + j]       = __float2half(xh*conf + nz*(1.f-conf));
            xc[ro + 128 + j] = __float2half(m);
            xc[ro + 256 + j] = __float2half(ds[r][j]);
        }
        __syncthreads();
    }
}

// ---- MFMA projection: px[r][768] = xc_chunk[r][0:384] @ Wcat^T + bcat ----
// 128x128 tile, 4 waves (2x2), BK=64, XOR-swizzled LDS (unit ^= row&7)
__global__ __launch_bounds__(256) void k_projm(const __half* __restrict__ xc,
                                               const __half* __restrict__ Wcat,
                                               const float* __restrict__ bcat,
                                               __half* __restrict__ px,
                                               int lTc, int chunk){
    __shared__ __align__(16) __half As[128*64];
    __shared__ __align__(16) __half Bs[128*64];
    const int tid = threadIdx.x;
    const int rblk = blockIdx.x * 128;
    const int ct0  = blockIdx.y * 128;
    const int mTc = (1<<lTc) - 1;

    // staging map: thread -> (row 0..127, half 0..1), 4x16B units
    const int row = tid >> 1;
    const int hf  = tid & 1;
    const int ar  = rblk + row;
    const long grow = ((long)(ar >> lTc))*TT + ((long)chunk << lTc) + (ar & mTc);
    const uint4* gA = (const uint4*)(xc + grow*384);
    const uint4* gB = (const uint4*)(Wcat + (size_t)(ct0 + row)*384);
    uint4* AsU = (uint4*)As;
    uint4* BsU = (uint4*)Bs;

    const int wv = tid >> 6;
    const int wm = wv >> 1, wn = wv & 1;
    const int l  = tid & 63;
    const int g  = l >> 4, r16 = l & 15;

    f32x4 acc[4][4];
    #pragma unroll
    for(int i=0;i<4;++i)
        #pragma unroll
        for(int jj=0;jj<4;++jj) acc[i][jj] = (f32x4){0.f,0.f,0.f,0.f};

    for(int bk=0; bk<6; ++bk){
        uint4 av[4], bv[4];
        #pragma unroll
        for(int u=0;u<4;++u){ av[u] = gA[bk*8 + hf*4 + u]; bv[u] = gB[bk*8 + hf*4 + u]; }
        if(bk) __syncthreads();           // previous reads done before overwrite
        #pragma unroll
        for(int u=0;u<4;++u){
            int uu = hf*4 + u;
            AsU[row*8 + (uu ^ (row&7))] = av[u];
            BsU[row*8 + (uu ^ (row&7))] = bv[u];
        }
        __syncthreads();
        #pragma unroll
        for(int ks=0;ks<2;++ks){
            f16x8 af[4], bf[4];
            #pragma unroll
            for(int mf=0;mf<4;++mf){
                int rr = wm*64 + mf*16 + r16;
                af[mf] = __builtin_bit_cast(f16x8, AsU[rr*8 + ((ks*4+g) ^ (rr&7))]);
            }
            #pragma unroll
            for(int nf=0;nf<4;++nf){
                int rr = wn*64 + nf*16 + r16;
                bf[nf] = __builtin_bit_cast(f16x8, BsU[rr*8 + ((ks*4+g) ^ (rr&7))]);
            }
            #pragma unroll
            for(int mf=0;mf<4;++mf)
                #pragma unroll
                for(int nf=0;nf<4;++nf)
                    acc[mf][nf] = __builtin_amdgcn_mfma_f32_16x16x32_f16(af[mf], bf[nf], acc[mf][nf], 0,0,0);
        }
    }
    // epilogue: C/D layout col=lane&15, row=(lane>>4)*4+reg (m89)
    #pragma unroll
    for(int nf=0; nf<4; ++nf){
        int col = ct0 + wn*64 + nf*16 + r16;
        float bb = bcat[col];
        #pragma unroll
        for(int mf=0; mf<4; ++mf){
            int r0 = rblk + wm*64 + mf*16 + g*4;
            f32x4 v = acc[mf][nf];
            #pragma unroll
            for(int e=0;e<4;++e)
                px[(size_t)(r0+e)*768 + col] = __float2half(v[e] + bb);
        }
    }
}

// ---- chunked GRU: register-resident f16 recurrent weights, 2 rows/block ----
__global__ __launch_bounds__(512,2) void k_gruc(const __half* __restrict__ pxc,
                                                const __half* __restrict__ Wrec,
                                                float* __restrict__ hstate,
                                                int Tc, int init){
    __shared__ __align__(16) __half h16[2][256];
    __shared__ __align__(16) __half rh16[2][256];
    __shared__ __align__(16) uint_t pxs[2][768];
    const int t  = threadIdx.x;
    const int j  = t >> 1;
    const int kh = t & 1;
    const long b0 = (long)blockIdx.x*2;
    const uint_t* Wr32 = (const uint_t*)Wrec;

    uint_t wz[64], wr[64], wh[64];
    #pragma unroll
    for(int q=0;q<64;++q){
        wz[q] = Wr32[(size_t)(      j)*128 + kh*64 + q];
        wr[q] = Wr32[(size_t)(256 + j)*128 + kh*64 + q];
        wh[q] = Wr32[(size_t)(512 + j)*128 + kh*64 + q];
    }

    const uint_t* px32 = (const uint_t*)pxc;
    auto ldpx = [&](int tl, int f)->uint_t{
        int row = (f >= 384); int off = f - row*384;
        return px32[((size_t)(b0+row)*Tc + tl)*384 + off];
    };

    float hreg0, hreg1;
    if(init){ hreg0 = 0.f; hreg1 = 0.f; }
    else    { hreg0 = hstate[(b0+0)*HH + j]; hreg1 = hstate[(b0+1)*HH + j]; }
    if(kh==0){ h16[0][j] = __float2half(hreg0); h16[1][j] = __float2half(hreg1); }
    pxs[0][t] = ldpx(0, t);
    if(t < 256) pxs[0][t+512] = ldpx(0, t+512);
    __syncthreads();

    const uint_t* h0p = ((const uint_t*)&h16[0][0]) + kh*64;
    const uint_t* h1p = ((const uint_t*)&h16[1][0]) + kh*64;
    const uint_t* r0p = ((const uint_t*)&rh16[0][0]) + kh*64;
    const uint_t* r1p = ((const uint_t*)&rh16[1][0]) + kh*64;

    for(int s=0; s<Tc; ++s){
        const int cur = s & 1;
        uint_t nf0 = 0, nf1 = 0;
        if(s < Tc-1){ nf0 = ldpx(s+1, t); if(t < 256) nf1 = ldpx(s+1, t+512); }

        const __half* pxcur = (const __half*)pxs[cur];
        float az0=0.f, az1=0.f, ar0=0.f, ar1=0.f;
        #pragma unroll
        for(int q=0;q<64;q+=4){
            uint4 hv0 = *(const uint4*)(h0p + q);
            uint4 hv1 = *(const uint4*)(h1p + q);
            az0=d2(wz[q+0],hv0.x,az0); ar0=d2(wr[q+0],hv0.x,ar0); az1=d2(wz[q+0],hv1.x,az1); ar1=d2(wr[q+0],hv1.x,ar1);
            az0=d2(wz[q+1],hv0.y,az0); ar0=d2(wr[q+1],hv0.y,ar0); az1=d2(wz[q+1],hv1.y,az1); ar1=d2(wr[q+1],hv1.y,ar1);
            az0=d2(wz[q+2],hv0.z,az0); ar0=d2(wr[q+2],hv0.z,ar0); az1=d2(wz[q+2],hv1.z,az1); ar1=d2(wr[q+2],hv1.z,ar1);
            az0=d2(wz[q+3],hv0.w,az0); ar0=d2(wr[q+3],hv0.w,ar0); az1=d2(wz[q+3],hv1.w,az1); ar1=d2(wr[q+3],hv1.w,ar1);
        }
        az0 += __shfl_xor(az0,1); az1 += __shfl_xor(az1,1);
        ar0 += __shfl_xor(ar0,1); ar1 += __shfl_xor(ar1,1);
        float z0 = sigmoidf_(__half2float(pxcur[        j]) + az0);
        float z1 = sigmoidf_(__half2float(pxcur[768   + j]) + az1);
        float r0 = sigmoidf_(__half2float(pxcur[256   + j]) + ar0);
        float r1 = sigmoidf_(__half2float(pxcur[768+256+j]) + ar1);
        if(kh==0){
            rh16[0][j] = __float2half(r0*hreg0);
            rh16[1][j] = __float2half(r1*hreg1);
        }
        __syncthreads();
        float ah0=0.f, ah1=0.f;
        #pragma unroll
        for(int q=0;q<64;q+=4){
            uint4 rv0 = *(const uint4*)(r0p + q);
            uint4 rv1 = *(const uint4*)(r1p + q);
            ah0=d2(wh[q+0],rv0.x,ah0); ah1=d2(wh[q+0],rv1.x,ah1);
            ah0=d2(wh[q+1],rv0.y,ah0); ah1=d2(wh[q+1],rv1.y,ah1);
            ah0=d2(wh[q+2],rv0.z,ah0); ah1=d2(wh[q+2],rv1.z,ah1);
            ah0=d2(wh[q+3],rv0.w,ah0); ah1=d2(wh[q+3],rv1.w,ah1);
        }
        ah0 += __shfl_xor(ah0,1); ah1 += __shfl_xor(ah1,1);
        float ht0 = tanhf_(__half2float(pxcur[512    + j]) + ah0);
        float ht1 = tanhf_(__half2float(pxcur[768+512+j]) + ah1);
        hreg0 = (1.f - z0)*hreg0 + z0*ht0;
        hreg1 = (1.f - z1)*hreg1 + z1*ht1;
        if(kh==0){
            h16[0][j] = __float2half(hreg0);
            h16[1][j] = __float2half(hreg1);
        }
        if(s < Tc-1){
            pxs[cur^1][t] = nf0;
            if(t < 256) pxs[cur^1][t+512] = nf1;
        }
        __syncthreads();
    }
    if(kh==0){
        hstate[(b0+0)*HH + j] = hreg0;
        hstate[(b0+1)*HH + j] = hreg1;
    }
}

// ---- LayerNorm + output projection ----
__global__ __launch_bounds__(256) void k_lnout(const float* __restrict__ hbuf,
    const float* __restrict__ lng, const float* __restrict__ lnb,
    const float* __restrict__ Wo, const float* __restrict__ bo,
    float* __restrict__ out){
    __shared__ __align__(16) float ln_s[HH];
    __shared__ float red[8];
    const int b = blockIdx.x, j = threadIdx.x;
    const float v = hbuf[(long)b*HH + j];
    float s = v, ss = v*v;
    const int lane = j & 63, w = j >> 6;
    for(int off=32; off>0; off>>=1){
        s  += __shfl_down(s,  off);
        ss += __shfl_down(ss, off);
    }
    if(lane == 0){ red[w] = s; red[4+w] = ss; }
    __syncthreads();
    float tot  = red[0]+red[1]+red[2]+red[3];
    float tot2 = red[4]+red[5]+red[6]+red[7];
    float mu  = tot  * (1.0f/HH);
    float var = tot2 * (1.0f/HH) - mu*mu;
    float rstd = rsqrtf(var + 1e-5f);
    ln_s[j] = (v - mu)*rstd*lng[j] + lnb[j];
    __syncthreads();
    if(j < OO){
        float acc = bo[j];
        const float4* w4 = (const float4*)(Wo + j*HH);
        const float4* l4 = (const float4*)ln_s;
        for(int k4=0;k4<HH/4;++k4){
            float4 wv = w4[k4], c = l4[k4];
            acc += wv.x*c.x + wv.y*c.y + wv.z*c.z + wv.w*c.w;
        }
        out[(long)b*OO + j] = acc;
    }
}

// ================= fallback path (round-0, proven, ~68MB ws) =================

__global__ __launch_bounds__(128) void k_emb_o(const float* __restrict__ x,
                                               const float* __restrict__ W,
                                               const float* __restrict__ bias,
                                               float* __restrict__ x1){
    __shared__ __align__(16) float xs[8][DD];
    const int j = threadIdx.x;
    const long row0 = (long)blockIdx.x * 32;
    const float bj = bias[j];
    const float4* W4 = (const float4*)(W + j*DD);
    for(int g=0; g<4; ++g){
        const long rbase = row0 + g*8;
        for(int r=0;r<8;++r) xs[r][j] = x[(rbase+r)*DD + j];
        __syncthreads();
        float acc[8];
        #pragma unroll
        for(int r=0;r<8;++r) acc[r] = bj;
        for(int k4=0;k4<DD/4;++k4){
            float4 w = W4[k4];
            #pragma unroll
            for(int r=0;r<8;++r){
                float4 c = ((const float4*)xs[r])[k4];
                acc[r] += c.x*w.x + c.y*w.y + c.z*w.z + c.w*w.w;
            }
        }
        for(int r=0;r<8;++r) x1[(rbase+r)*DD + j] = acc[r];
        __syncthreads();
    }
}

__global__ __launch_bounds__(128) void k_mean_o(const float* __restrict__ x1,
                                                float* __restrict__ xmean){
    const int j = threadIdx.x;
    const int b = blockIdx.x;
    const float* p = x1 + (long)b*TT*DD + j;
    float s = 0.f;
    for(int t=0;t<TT;++t) s += p[(long)t*DD];
    xmean[b*DD + j] = s * (1.0f/TT);
}

__global__ __launch_bounds__(128) void k_gate_o(float* __restrict__ xf,
    const float* __restrict__ xmask, const float* __restrict__ xdelta,
    const float* __restrict__ noise,
    const float* __restrict__ Wd1, const float* __restrict__ bd1,
    const float* __restrict__ Wd2, const float* __restrict__ bd2,
    const float* __restrict__ Wc,  const float* __restrict__ bc,
    const float* __restrict__ xmean){
    __shared__ __align__(16) float ds[8][DD];
    __shared__ __align__(16) float t1s[8][DD];
    __shared__ __align__(16) float xhs[8][DD];
    const int j = threadIdx.x;
    const long row0 = (long)blockIdx.x * 32;
    const int b = (int)(row0 >> 8);
    const float xm = xmean[b*DD + j];
    const float b1 = bd1[j], b2 = bd2[j], bcj = bc[j];
    const float4* Wd1_4 = (const float4*)(Wd1 + j*DD);
    const float4* Wd2_4 = (const float4*)(Wd2 + j*DD);
    const float4* Wc_4  = (const float4*)(Wc  + j*2*DD);
    for(int g=0; g<4; ++g){
        const long rbase = row0 + g*8;
        for(int r=0;r<8;++r)
            ds[r][j] = fminf(fmaxf(xdelta[(rbase+r)*DD + j], 0.f), 100.f);
        __syncthreads();
        float acc[8];
        #pragma unroll
        for(int r=0;r<8;++r) acc[r] = b1;
        for(int k4=0;k4<DD/4;++k4){
            float4 w = Wd1_4[k4];
            #pragma unroll
            for(int r=0;r<8;++r){
                float4 c = ((const float4*)ds[r])[k4];
                acc[r] += c.x*w.x + c.y*w.y + c.z*w.z + c.w*w.w;
            }
        }
        for(int r=0;r<8;++r) t1s[r][j] = fmaxf(acc[r], 0.f);
        __syncthreads();
        #pragma unroll
        for(int r=0;r<8;++r) acc[r] = b2;
        for(int k4=0;k4<DD/4;++k4){
            float4 w = Wd2_4[k4];
            #pragma unroll
            for(int r=0;r<8;++r){
                float4 c = ((const float4*)t1s[r])[k4];
                acc[r] += c.x*w.x + c.y*w.y + c.z*w.z + c.w*w.w;
            }
        }
        for(int r=0;r<8;++r){
            float gmm = sigmoidf_(acc[r]);
            float m  = xmask[(rbase+r)*DD + j];
            float xv = xf[(rbase+r)*DD + j];
            xhs[r][j] = m*xv + (1.f-m)*gmm*xm;
        }
        __syncthreads();
        #pragma unroll
        for(int r=0;r<8;++r) acc[r] = bcj;
        for(int k4=0;k4<DD/4;++k4){
            float4 w = Wc_4[k4];
            #pragma unroll
            for(int r=0;r<8;++r){
                float4 c = ((const float4*)xhs[r])[k4];
                acc[r] += c.x*w.x + c.y*w.y + c.z*w.z + c.w*w.w;
            }
        }
        for(int k4=0;k4<DD/4;++k4){
            float4 w = Wc_4[DD/4 + k4];
            #pragma unroll
            for(int r=0;r<8;++r){
                float4 c = ((const float4*)ds[r])[k4];
                acc[r] += c.x*w.x + c.y*w.y + c.z*w.z + c.w*w.w;
            }
        }
        for(int r=0;r<8;++r){
            float conf = sigmoidf_(acc[r]);
            float xh = xhs[r][j];
            float nz = noise[(rbase+r)*DD + j];
            xf[(rbase+r)*DD + j] = xh*conf + nz*(1.f-conf);
        }
        __syncthreads();
    }
}

__global__ __launch_bounds__(1024) void k_gru_o(const float* __restrict__ xf,
    const float* __restrict__ xmask, const float* __restrict__ xdelta,
    const float* __restrict__ Wz, const float* __restrict__ bz,
    const float* __restrict__ Wr, const float* __restrict__ br,
    const float* __restrict__ Wh, const float* __restrict__ bh,
    float* __restrict__ hout){
    __shared__ __align__(16) float xcs[4][KH];
    __shared__ __align__(16) float rh[4][HH];
    const int tid = threadIdx.x;
    const int j  = tid & 255;
    const int bl = tid >> 8;
    const long bbase = (long)blockIdx.x * 4;
    xcs[bl][384 + j] = 0.f;
    const float bzj = bz[j], brj = br[j], bhj = bh[j];
    const float4* Wz4 = (const float4*)(Wz + (long)j*KH);
    const float4* Wr4 = (const float4*)(Wr + (long)j*KH);
    const float4* Wh4 = (const float4*)(Wh + (long)j*KH);
    __syncthreads();
    for(int t=0;t<TT;++t){
        if(tid < 4*DD){
            int sb = tid >> 7, k = tid & 127;
            long row = (bbase + sb)*TT + t;
            xcs[sb][k]       = xf[row*DD + k];
            xcs[sb][128 + k] = xmask[row*DD + k];
            xcs[sb][256 + k] = fminf(fmaxf(xdelta[row*DD + k], 0.f), 100.f);
        }
        __syncthreads();
        const float4* cb = (const float4*)xcs[bl];
        float az = bzj, ar = brj;
        for(int k4=0;k4<KH/4;++k4){
            float4 wz = Wz4[k4], wrr = Wr4[k4];
            float4 v = cb[k4];
            az += v.x*wz.x + v.y*wz.y + v.z*wz.z + v.w*wz.w;
            ar += v.x*wrr.x + v.y*wrr.y + v.z*wrr.z + v.w*wrr.w;
        }
        float z = sigmoidf_(az);
        float r = sigmoidf_(ar);
        rh[bl][j] = r * xcs[bl][384 + j];
        __syncthreads();
        float ah = bhj;
        for(int k4=0;k4<96;++k4){
            float4 wh = Wh4[k4];
            float4 v = cb[k4];
            ah += v.x*wh.x + v.y*wh.y + v.z*wh.z + v.w*wh.w;
        }
        const float4* rp = (const float4*)rh[bl];
        for(int k4=0;k4<64;++k4){
            float4 wh = Wh4[96 + k4];
            float4 v = rp[k4];
            ah += v.x*wh.x + v.y*wh.y + v.z*wh.z + v.w*wh.w;
        }
        float ht = tanhf(ah);
        float hold = xcs[bl][384 + j];
        float hn = (1.f - z)*hold + z*ht;
        xcs[bl][384 + j] = hn;
        __syncthreads();
    }
    hout[(bbase + bl)*HH + j] = xcs[bl][384 + j];
}

// ================= launch =================

extern "C" void kernel_launch(void* const* d_in, const int* in_sizes, int n_in,
                              void* d_out, int out_size, void* d_ws, size_t ws_size,
                              hipStream_t stream){
    const float* x      = (const float*)d_in[0];
    const float* xmask  = (const float*)d_in[1];
    const float* xdelta = (const float*)d_in[2];
    const float* noise  = (const float*)d_in[3];
    const float* W_emb  = (const float*)d_in[4];
    const float* b_emb  = (const float*)d_in[5];
    const float* W_d1   = (const float*)d_in[6];
    const float* b_d1   = (const float*)d_in[7];
    const float* W_d2   = (const float*)d_in[8];
    const float* b_d2   = (const float*)d_in[9];
    const float* W_c    = (const float*)d_in[10];
    const float* b_c    = (const float*)d_in[11];
    const float* W_z    = (const float*)d_in[12];
    const float* b_z    = (const float*)d_in[13];
    const float* W_r    = (const float*)d_in[14];
    const float* b_r    = (const float*)d_in[15];
    const float* W_h    = (const float*)d_in[16];
    const float* b_h    = (const float*)d_in[17];
    const float* ln_g   = (const float*)d_in[18];
    const float* ln_b   = (const float*)d_in[19];
    const float* W_o    = (const float*)d_in[20];
    const float* b_o    = (const float*)d_in[21];
    float* out = (float*)d_out;
    char* ws = (char*)d_ws;

    // pick largest power-of-2 time-chunk that fits (<=128)
    int Tc = 0, lTc = 0;
    {
        const int cand[3]  = {128, 64, 32};
        const int lcand[3] = {7, 6, 5};
        for(int i=0;i<3;++i){
            size_t need = SZ_XC + (size_t)cand[i]*786432 + TAIL_SZ;
            if(ws_size >= need){ Tc = cand[i]; lTc = lcand[i]; break; }
        }
    }

    if(Tc > 0){
        __half* xc    = (__half*)(ws);
        char*   p     = ws + SZ_XC;
        __half* pxc   = (__half*)p;              p += (size_t)Tc*786432;
        __half* Wcat  = (__half*)p;              p += 589824;
        __half* Wrec  = (__half*)p;              p += 393216;
        float*  bcat  = (float*)p;               p += 3072;
        float*  xmean = (float*)p;               p += 262144;
        float*  hstate= (float*)p;

        k_wprep<<<dim3(768),   dim3(128), 0, stream>>>(W_z,W_r,W_h,b_z,b_r,b_h, Wcat, Wrec, bcat);
        k_emb  <<<dim3(BT/32), dim3(128), 0, stream>>>(x, W_emb, b_emb, xc);
        k_mean <<<dim3(BB),    dim3(128), 0, stream>>>(xc, xmean);
        k_gate <<<dim3(BT/32), dim3(128), 0, stream>>>(xc, xmask, xdelta, noise,
                                                       W_d1,b_d1,W_d2,b_d2,W_c,b_c, xmean);
        const int nchunk = TT / Tc;
        for(int c=0; c<nchunk; ++c){
            k_projm<<<dim3(BB*Tc/128, 6), dim3(256), 0, stream>>>(xc, Wcat, bcat, pxc, lTc, c);
            k_gruc <<<dim3(BB/2), dim3(512), 0, stream>>>(pxc, Wrec, hstate, Tc, c==0 ? 1 : 0);
        }
        k_lnout<<<dim3(BB), dim3(256), 0, stream>>>(hstate, ln_g, ln_b, W_o, b_o, out);
    } else {
        float* xf    = (float*)ws;
        float* xmean = (float*)(ws + (size_t)BT*DD*4);
        float* hbuf  = (float*)(ws + (size_t)BT*DD*4 + (size_t)BB*DD*4);
        k_emb_o  <<<dim3(BT/32), dim3(128), 0, stream>>>(x, W_emb, b_emb, xf);
        k_mean_o <<<dim3(BB),    dim3(128), 0, stream>>>(xf, xmean);
        k_gate_o <<<dim3(BT/32), dim3(128), 0, stream>>>(xf, xmask, xdelta, noise,
                                                         W_d1,b_d1,W_d2,b_d2,W_c,b_c, xmean);
        k_gru_o  <<<dim3(BB/4),  dim3(1024),0, stream>>>(xf, xmask, xdelta,
                                                         W_z,b_z,W_r,b_r,W_h,b_h, hbuf);
        k_lnout  <<<dim3(BB),    dim3(256), 0, stream>>>(hbuf, ln_g, ln_b, W_o, b_o, out);
    }
}

// Round 5
// 1387.839 us; speedup vs baseline: 42.4827x; 1.3839x over previous
//
#include <hip/hip_runtime.h>
#include <hip/hip_fp16.h>
#include <math.h>

#define BB 512
#define TT 256
#define DD 128
#define HH 256
#define OO 128
#define KH 640   // 3*D + H
#define BT (BB*TT)

typedef unsigned int uint_t;
typedef _Float16 f16x8 __attribute__((ext_vector_type(8)));
typedef float f32x4 __attribute__((ext_vector_type(4)));

__device__ __forceinline__ float sigmoidf_(float x){ return 1.0f/(1.0f+__expf(-x)); }
__device__ __forceinline__ float tanhf_(float x){ float e = __expf(-2.0f*x); return 2.0f/(1.0f+e) - 1.0f; }
__device__ __forceinline__ float clipd_(float x){ return fminf(fmaxf(x, 0.f), 100.f); }

typedef _Float16 h2v __attribute__((ext_vector_type(2)));
__device__ __forceinline__ float d2(uint_t a, uint_t b, float c){
#if __has_builtin(__builtin_amdgcn_fdot2)
    return __builtin_amdgcn_fdot2(__builtin_bit_cast(h2v, a), __builtin_bit_cast(h2v, b), c, false);
#else
    __half2 ha = __builtin_bit_cast(__half2, a);
    __half2 hb = __builtin_bit_cast(__half2, b);
    return c + __half2float(ha.x)*__half2float(hb.x) + __half2float(ha.y)*__half2float(hb.y);
#endif
}
__device__ __forceinline__ uint_t pack2(float a, float b){
    __half2 h; h.x = __float2half(a); h.y = __float2half(b);
    return __builtin_bit_cast(uint_t, h);
}

// ---- ws layout ----
// xc : BT*384 f16 (rows [x_final|mask|delta])  = 100,663,296
// px : 512*Tc*768 f16 = Tc*786,432
// tail: Wcat 589824 | Wrec 393216 | bcat 3072 | xmean 262144 | hstate 524288
//       | Wembh 32768 | Wd1h 32768 | Wd2h 32768 | Wch 65536
static const size_t SZ_XC   = (size_t)BT*384*2;
static const size_t TAIL_SZ = 589824 + 393216 + 3072 + 262144 + 524288 + 32768*3 + 65536;

// ---- weight prep: GRU weights f32 -> f16, split cat(384)/rec(256) ----
__global__ __launch_bounds__(128) void k_wprep(const float* __restrict__ Wz, const float* __restrict__ Wr,
                                               const float* __restrict__ Wh, const float* __restrict__ bz,
                                               const float* __restrict__ br, const float* __restrict__ bh,
                                               __half* __restrict__ Wcat, __half* __restrict__ Wrec,
                                               float* __restrict__ bcat){
    int gj = blockIdx.x; int j = gj & 255;
    const float* src  = (gj < 256 ? Wz : (gj < 512 ? Wr : Wh)) + (size_t)j*KH;
    const float* bsrc = (gj < 256 ? bz : (gj < 512 ? br : bh));
    for(int k=threadIdx.x; k<384; k+=128) Wcat[(size_t)gj*384 + k] = __float2half(src[k]);
    for(int k=threadIdx.x; k<256; k+=128) Wrec[(size_t)gj*256 + k] = __float2half(src[384+k]);
    if(threadIdx.x==0) bcat[gj] = bsrc[j];
}

// ---- small weights f32 -> f16 ----
__global__ __launch_bounds__(256) void k_cvt(const float* __restrict__ a, const float* __restrict__ b,
                                             const float* __restrict__ c, const float* __restrict__ d,
                                             __half* __restrict__ oa, __half* __restrict__ ob,
                                             __half* __restrict__ oc, __half* __restrict__ od){
    int i = blockIdx.x*256 + threadIdx.x;   // grid 128 -> 32768 threads
    if(i < 16384){
        oa[i] = __float2half(a[i]);
        ob[i] = __float2half(b[i]);
        oc[i] = __float2half(c[i]);
    }
    od[i] = __float2half(d[i]);
}

// ---- MFMA emb: x1 = x @ Wemb^T + b -> xc[.,0:128] ----
__global__ __launch_bounds__(256,4) void k_embm(const float* __restrict__ x,
                                                const __half* __restrict__ Wh,
                                                const float* __restrict__ bias,
                                                __half* __restrict__ xc){
    __shared__ __align__(16) uint4 TxU[128*16];
    const int tid = threadIdx.x;
    const long row0 = (long)blockIdx.x*128;
    {
        const int srow = tid>>1, shalf = tid&1;
        const long gr = row0 + srow;
        const float4* gx = (const float4*)(x + gr*DD + shalf*64);
        #pragma unroll
        for(int u=0;u<8;++u){
            float4 a = gx[u*2], q = gx[u*2+1];
            uint4 pk;
            pk.x = pack2(a.x,a.y); pk.y = pack2(a.z,a.w);
            pk.z = pack2(q.x,q.y); pk.w = pack2(q.z,q.w);
            int unit = shalf*8 + u;
            TxU[srow*16 + (unit ^ (srow&7))] = pk;
        }
    }
    __syncthreads();
    const int wv = tid>>6, lane = tid&63, g = lane>>4, r16 = lane&15;
    const int wrow0 = wv*32;
    const uint4* WU = (const uint4*)Wh;
    f32x4 acc[2][8];
    #pragma unroll
    for(int i=0;i<2;++i)
        #pragma unroll
        for(int jj=0;jj<8;++jj) acc[i][jj] = (f32x4){0.f,0.f,0.f,0.f};
    #pragma unroll
    for(int ks=0;ks<4;++ks){
        f16x8 af[2], bf[8];
        #pragma unroll
        for(int mf=0;mf<2;++mf){
            int rr = wrow0 + mf*16 + r16;
            af[mf] = __builtin_bit_cast(f16x8, TxU[rr*16 + ((ks*4+g) ^ (rr&7))]);
        }
        #pragma unroll
        for(int nf=0;nf<8;++nf){
            int col = nf*16 + r16;
            bf[nf] = __builtin_bit_cast(f16x8, WU[col*16 + ks*4 + g]);
        }
        #pragma unroll
        for(int mf=0;mf<2;++mf)
            #pragma unroll
            for(int nf=0;nf<8;++nf)
                acc[mf][nf] = __builtin_amdgcn_mfma_f32_16x16x32_f16(af[mf], bf[nf], acc[mf][nf], 0,0,0);
    }
    #pragma unroll
    for(int nf=0;nf<8;++nf){
        int col = nf*16 + r16;
        float bb = bias[col];
        #pragma unroll
        for(int mf=0;mf<2;++mf){
            int rowb = wrow0 + mf*16 + g*4;
            f32x4 v = acc[mf][nf];
            #pragma unroll
            for(int e=0;e<4;++e)
                xc[(size_t)(row0+rowb+e)*384 + col] = __float2half(v[e] + bb);
        }
    }
}

// ---- vectorized mean over t of xc[.,0:128] ----
__global__ __launch_bounds__(256) void k_meanv(const __half* __restrict__ xc,
                                               float* __restrict__ xmean){
    __shared__ float red[16][128];
    const int tid = threadIdx.x;
    const int trow = tid>>4, c8 = tid&15;
    const int b = blockIdx.x;
    float s[8];
    #pragma unroll
    for(int e=0;e<8;++e) s[e] = 0.f;
    for(int t=trow; t<TT; t+=16){
        uint4 v = *(const uint4*)(xc + ((size_t)b*TT + t)*384 + c8*8);
        const __half* hp = (const __half*)&v;
        #pragma unroll
        for(int e=0;e<8;++e) s[e] += __half2float(hp[e]);
    }
    #pragma unroll
    for(int e=0;e<8;++e) red[trow][c8*8+e] = s[e];
    __syncthreads();
    if(tid < 128){
        float tot = 0.f;
        #pragma unroll
        for(int r=0;r<16;++r) tot += red[r][tid];
        xmean[b*DD + tid] = tot*(1.0f/TT);
    }
}

// ---- fused MFMA gate chain: fills xc row = [x_final | mask | delta] ----
__global__ __launch_bounds__(256,2) void k_gatem(__half* __restrict__ xc,
    const float* __restrict__ xmask, const float* __restrict__ xdelta,
    const float* __restrict__ noise,
    const __half* __restrict__ Wd1h, const float* __restrict__ bd1,
    const __half* __restrict__ Wd2h, const float* __restrict__ bd2,
    const __half* __restrict__ Wch,  const float* __restrict__ bc,
    const float* __restrict__ xmean){
    __shared__ __align__(16) uint4 TdU[128*16];
    __shared__ __align__(16) uint4 TtU[128*16];
    __half* Tth = (__half*)TtU;
    const int tid = threadIdx.x;
    const long row0 = (long)blockIdx.x*128;
    const int b = (int)(row0 >> 8);

    // staging: delta (clipped) -> TdU + xc units 32..47 ; mask -> xc units 16..31
    {
        const int srow = tid>>1, shalf = tid&1;
        const long gr = row0 + srow;
        const float4* gd = (const float4*)(xdelta + gr*DD + shalf*64);
        const float4* gm = (const float4*)(xmask  + gr*DD + shalf*64);
        uint4* xcu = (uint4*)(xc + gr*384);
        #pragma unroll
        for(int u=0;u<8;++u){
            float4 a = gd[u*2], q = gd[u*2+1];
            uint4 pk;
            pk.x = pack2(clipd_(a.x), clipd_(a.y));
            pk.y = pack2(clipd_(a.z), clipd_(a.w));
            pk.z = pack2(clipd_(q.x), clipd_(q.y));
            pk.w = pack2(clipd_(q.z), clipd_(q.w));
            int unit = shalf*8 + u;
            TdU[srow*16 + (unit ^ (srow&7))] = pk;
            xcu[32 + unit] = pk;
        }
        #pragma unroll
        for(int u=0;u<8;++u){
            float4 a = gm[u*2], q = gm[u*2+1];
            uint4 pk;
            pk.x = pack2(a.x,a.y); pk.y = pack2(a.z,a.w);
            pk.z = pack2(q.x,q.y); pk.w = pack2(q.z,q.w);
            xcu[16 + shalf*8 + u] = pk;
        }
    }
    __syncthreads();

    const int wv = tid>>6, lane = tid&63, g = lane>>4, r16 = lane&15;
    const int wrow0 = wv*32;
    const uint4* W1U = (const uint4*)Wd1h;
    const uint4* W2U = (const uint4*)Wd2h;
    const uint4* WcU = (const uint4*)Wch;
    f32x4 acc[2][8];

    // ---- stage 2: t1 = relu(d @ Wd1^T + b1) -> Tt ----
    #pragma unroll
    for(int i=0;i<2;++i)
        #pragma unroll
        for(int jj=0;jj<8;++jj) acc[i][jj] = (f32x4){0.f,0.f,0.f,0.f};
    #pragma unroll
    for(int ks=0;ks<4;++ks){
        f16x8 af[2], bf[8];
        #pragma unroll
        for(int mf=0;mf<2;++mf){
            int rr = wrow0 + mf*16 + r16;
            af[mf] = __builtin_bit_cast(f16x8, TdU[rr*16 + ((ks*4+g) ^ (rr&7))]);
        }
        #pragma unroll
        for(int nf=0;nf<8;++nf){
            int col = nf*16 + r16;
            bf[nf] = __builtin_bit_cast(f16x8, W1U[col*16 + ks*4 + g]);
        }
        #pragma unroll
        for(int mf=0;mf<2;++mf)
            #pragma unroll
            for(int nf=0;nf<8;++nf)
                acc[mf][nf] = __builtin_amdgcn_mfma_f32_16x16x32_f16(af[mf], bf[nf], acc[mf][nf], 0,0,0);
    }
    #pragma unroll
    for(int nf=0;nf<8;++nf){
        int col = nf*16 + r16;
        float bb = bd1[col];
        int u = col>>3, cl = col&7;
        #pragma unroll
        for(int mf=0;mf<2;++mf){
            int rowb = wrow0 + mf*16 + g*4;
            f32x4 v = acc[mf][nf];
            #pragma unroll
            for(int e=0;e<4;++e){
                int rr = rowb + e;
                float t = v[e] + bb; t = t > 0.f ? t : 0.f;
                Tth[(rr*16 + (u ^ (rr&7)))*8 + cl] = __float2half(t);
            }
        }
    }

    // ---- stage 3: gamma = sigmoid(t1 @ Wd2^T + b2) (own rows only; no barrier) ----
    #pragma unroll
    for(int i=0;i<2;++i)
        #pragma unroll
        for(int jj=0;jj<8;++jj) acc[i][jj] = (f32x4){0.f,0.f,0.f,0.f};
    #pragma unroll
    for(int ks=0;ks<4;++ks){
        f16x8 af[2], bf[8];
        #pragma unroll
        for(int mf=0;mf<2;++mf){
            int rr = wrow0 + mf*16 + r16;
            af[mf] = __builtin_bit_cast(f16x8, TtU[rr*16 + ((ks*4+g) ^ (rr&7))]);
        }
        #pragma unroll
        for(int nf=0;nf<8;++nf){
            int col = nf*16 + r16;
            bf[nf] = __builtin_bit_cast(f16x8, W2U[col*16 + ks*4 + g]);
        }
        #pragma unroll
        for(int mf=0;mf<2;++mf)
            #pragma unroll
            for(int nf=0;nf<8;++nf)
                acc[mf][nf] = __builtin_amdgcn_mfma_f32_16x16x32_f16(af[mf], bf[nf], acc[mf][nf], 0,0,0);
    }

    // ---- stage 4: x_hat = m*x1 + (1-m)*gamma*xmean -> Tt ----
    #pragma unroll
    for(int nf=0;nf<8;++nf){
        int col = nf*16 + r16;
        float b2 = bd2[col];
        float xm = xmean[b*DD + col];
        int u = col>>3, cl = col&7;
        #pragma unroll
        for(int mf=0;mf<2;++mf){
            int rowb = wrow0 + mf*16 + g*4;
            f32x4 v = acc[mf][nf];
            #pragma unroll
            for(int e=0;e<4;++e){
                int rr = rowb + e;
                long grow = row0 + rr;
                float m  = xmask[grow*DD + col];
                float x1 = __half2float(xc[grow*384 + col]);
                float gmm = sigmoidf_(v[e] + b2);
                float xh = m*x1 + (1.f-m)*gmm*xm;
                Tth[(rr*16 + (u ^ (rr&7)))*8 + cl] = __float2half(xh);
            }
        }
    }

    // ---- stage 5: conf = sigmoid(xh@Wc[:, :128]^T + d@Wc[:,128:]^T + bc) ----
    #pragma unroll
    for(int i=0;i<2;++i)
        #pragma unroll
        for(int jj=0;jj<8;++jj) acc[i][jj] = (f32x4){0.f,0.f,0.f,0.f};
    #pragma unroll
    for(int ks=0;ks<4;++ks){
        f16x8 af[2], bf[8];
        #pragma unroll
        for(int mf=0;mf<2;++mf){
            int rr = wrow0 + mf*16 + r16;
            af[mf] = __builtin_bit_cast(f16x8, TtU[rr*16 + ((ks*4+g) ^ (rr&7))]);
        }
        #pragma unroll
        for(int nf=0;nf<8;++nf){
            int col = nf*16 + r16;
            bf[nf] = __builtin_bit_cast(f16x8, WcU[col*32 + ks*4 + g]);
        }
        #pragma unroll
        for(int mf=0;mf<2;++mf)
            #pragma unroll
            for(int nf=0;nf<8;++nf)
                acc[mf][nf] = __builtin_amdgcn_mfma_f32_16x16x32_f16(af[mf], bf[nf], acc[mf][nf], 0,0,0);
    }
    #pragma unroll
    for(int ks=0;ks<4;++ks){
        f16x8 af[2], bf[8];
        #pragma unroll
        for(int mf=0;mf<2;++mf){
            int rr = wrow0 + mf*16 + r16;
            af[mf] = __builtin_bit_cast(f16x8, TdU[rr*16 + ((ks*4+g) ^ (rr&7))]);
        }
        #pragma unroll
        for(int nf=0;nf<8;++nf){
            int col = nf*16 + r16;
            bf[nf] = __builtin_bit_cast(f16x8, WcU[col*32 + 16 + ks*4 + g]);
        }
        #pragma unroll
        for(int mf=0;mf<2;++mf)
            #pragma unroll
            for(int nf=0;nf<8;++nf)
                acc[mf][nf] = __builtin_amdgcn_mfma_f32_16x16x32_f16(af[mf], bf[nf], acc[mf][nf], 0,0,0);
    }

    // ---- stage 6: x_final -> xc[.,0:128] ----
    #pragma unroll
    for(int nf=0;nf<8;++nf){
        int col = nf*16 + r16;
        float bcc = bc[col];
        int u = col>>3, cl = col&7;
        #pragma unroll
        for(int mf=0;mf<2;++mf){
            int rowb = wrow0 + mf*16 + g*4;
            f32x4 v = acc[mf][nf];
            #pragma unroll
            for(int e=0;e<4;++e){
                int rr = rowb + e;
                long grow = row0 + rr;
                float conf = sigmoidf_(v[e] + bcc);
                float xh = __half2float(Tth[(rr*16 + (u ^ (rr&7)))*8 + cl]);
                float nz = noise[grow*DD + col];
                xc[grow*384 + col] = __float2half(xh*conf + nz*(1.f-conf));
            }
        }
    }
}

// ---- MFMA projection: px[r][768] = xc_chunk[r][0:384] @ Wcat^T + bcat ----
__global__ __launch_bounds__(256) void k_projm(const __half* __restrict__ xc,
                                               const __half* __restrict__ Wcat,
                                               const float* __restrict__ bcat,
                                               __half* __restrict__ px,
                                               int lTc, int chunk){
    __shared__ __align__(16) __half As[128*64];
    __shared__ __align__(16) __half Bs[128*64];
    const int tid = threadIdx.x;
    const int rblk = blockIdx.x * 128;
    const int ct0  = blockIdx.y * 128;
    const int mTc = (1<<lTc) - 1;

    const int row = tid >> 1;
    const int hf  = tid & 1;
    const int ar  = rblk + row;
    const long grow = ((long)(ar >> lTc))*TT + ((long)chunk << lTc) + (ar & mTc);
    const uint4* gA = (const uint4*)(xc + grow*384);
    const uint4* gB = (const uint4*)(Wcat + (size_t)(ct0 + row)*384);
    uint4* AsU = (uint4*)As;
    uint4* BsU = (uint4*)Bs;

    const int wv = tid >> 6;
    const int wm = wv >> 1, wn = wv & 1;
    const int l  = tid & 63;
    const int g  = l >> 4, r16 = l & 15;

    f32x4 acc[4][4];
    #pragma unroll
    for(int i=0;i<4;++i)
        #pragma unroll
        for(int jj=0;jj<4;++jj) acc[i][jj] = (f32x4){0.f,0.f,0.f,0.f};

    for(int bk=0; bk<6; ++bk){
        uint4 av[4], bv[4];
        #pragma unroll
        for(int u=0;u<4;++u){ av[u] = gA[bk*8 + hf*4 + u]; bv[u] = gB[bk*8 + hf*4 + u]; }
        if(bk) __syncthreads();
        #pragma unroll
        for(int u=0;u<4;++u){
            int uu = hf*4 + u;
            AsU[row*8 + (uu ^ (row&7))] = av[u];
            BsU[row*8 + (uu ^ (row&7))] = bv[u];
        }
        __syncthreads();
        #pragma unroll
        for(int ks=0;ks<2;++ks){
            f16x8 af[4], bf[4];
            #pragma unroll
            for(int mf=0;mf<4;++mf){
                int rr = wm*64 + mf*16 + r16;
                af[mf] = __builtin_bit_cast(f16x8, AsU[rr*8 + ((ks*4+g) ^ (rr&7))]);
            }
            #pragma unroll
            for(int nf=0;nf<4;++nf){
                int rr = wn*64 + nf*16 + r16;
                bf[nf] = __builtin_bit_cast(f16x8, BsU[rr*8 + ((ks*4+g) ^ (rr&7))]);
            }
            #pragma unroll
            for(int mf=0;mf<4;++mf)
                #pragma unroll
                for(int nf=0;nf<4;++nf)
                    acc[mf][nf] = __builtin_amdgcn_mfma_f32_16x16x32_f16(af[mf], bf[nf], acc[mf][nf], 0,0,0);
        }
    }
    #pragma unroll
    for(int nf=0; nf<4; ++nf){
        int col = ct0 + wn*64 + nf*16 + r16;
        float bb = bcat[col];
        #pragma unroll
        for(int mf=0; mf<4; ++mf){
            int r0 = rblk + wm*64 + mf*16 + g*4;
            f32x4 v = acc[mf][nf];
            #pragma unroll
            for(int e=0;e<4;++e)
                px[(size_t)(r0+e)*768 + col] = __float2half(v[e] + bb);
        }
    }
}

// ---- chunked GRU: register-resident f16 recurrent weights, 2 rows/block ----
__global__ __launch_bounds__(512,2) void k_gruc(const __half* __restrict__ pxc,
                                                const __half* __restrict__ Wrec,
                                                float* __restrict__ hstate,
                                                int Tc, int init){
    __shared__ __align__(16) __half h16[2][256];
    __shared__ __align__(16) __half rh16[2][256];
    __shared__ __align__(16) uint_t pxs[2][768];
    const int t  = threadIdx.x;
    const int j  = t >> 1;
    const int kh = t & 1;
    const long b0 = (long)blockIdx.x*2;
    const uint_t* Wr32 = (const uint_t*)Wrec;

    uint_t wz[64], wr[64], wh[64];
    #pragma unroll
    for(int q=0;q<64;++q){
        wz[q] = Wr32[(size_t)(      j)*128 + kh*64 + q];
        wr[q] = Wr32[(size_t)(256 + j)*128 + kh*64 + q];
        wh[q] = Wr32[(size_t)(512 + j)*128 + kh*64 + q];
    }

    const uint_t* px32 = (const uint_t*)pxc;
    auto ldpx = [&](int tl, int f)->uint_t{
        int row = (f >= 384); int off = f - row*384;
        return px32[((size_t)(b0+row)*Tc + tl)*384 + off];
    };

    float hreg0, hreg1;
    if(init){ hreg0 = 0.f; hreg1 = 0.f; }
    else    { hreg0 = hstate[(b0+0)*HH + j]; hreg1 = hstate[(b0+1)*HH + j]; }
    if(kh==0){ h16[0][j] = __float2half(hreg0); h16[1][j] = __float2half(hreg1); }
    pxs[0][t] = ldpx(0, t);
    if(t < 256) pxs[0][t+512] = ldpx(0, t+512);
    __syncthreads();

    const uint_t* h0p = ((const uint_t*)&h16[0][0]) + kh*64;
    const uint_t* h1p = ((const uint_t*)&h16[1][0]) + kh*64;
    const uint_t* r0p = ((const uint_t*)&rh16[0][0]) + kh*64;
    const uint_t* r1p = ((const uint_t*)&rh16[1][0]) + kh*64;

    for(int s=0; s<Tc; ++s){
        const int cur = s & 1;
        uint_t nf0 = 0, nf1 = 0;
        if(s < Tc-1){ nf0 = ldpx(s+1, t); if(t < 256) nf1 = ldpx(s+1, t+512); }

        const __half* pxcur = (const __half*)pxs[cur];
        float az0=0.f, az1=0.f, ar0=0.f, ar1=0.f;
        #pragma unroll
        for(int q=0;q<64;q+=4){
            uint4 hv0 = *(const uint4*)(h0p + q);
            uint4 hv1 = *(const uint4*)(h1p + q);
            az0=d2(wz[q+0],hv0.x,az0); ar0=d2(wr[q+0],hv0.x,ar0); az1=d2(wz[q+0],hv1.x,az1); ar1=d2(wr[q+0],hv1.x,ar1);
            az0=d2(wz[q+1],hv0.y,az0); ar0=d2(wr[q+1],hv0.y,ar0); az1=d2(wz[q+1],hv1.y,az1); ar1=d2(wr[q+1],hv1.y,ar1);
            az0=d2(wz[q+2],hv0.z,az0); ar0=d2(wr[q+2],hv0.z,ar0); az1=d2(wz[q+2],hv1.z,az1); ar1=d2(wr[q+2],hv1.z,ar1);
            az0=d2(wz[q+3],hv0.w,az0); ar0=d2(wr[q+3],hv0.w,ar0); az1=d2(wz[q+3],hv1.w,az1); ar1=d2(wr[q+3],hv1.w,ar1);
        }
        az0 += __shfl_xor(az0,1); az1 += __shfl_xor(az1,1);
        ar0 += __shfl_xor(ar0,1); ar1 += __shfl_xor(ar1,1);
        float z0 = sigmoidf_(__half2float(pxcur[        j]) + az0);
        float z1 = sigmoidf_(__half2float(pxcur[768   + j]) + az1);
        float r0 = sigmoidf_(__half2float(pxcur[256   + j]) + ar0);
        float r1 = sigmoidf_(__half2float(pxcur[768+256+j]) + ar1);
        if(kh==0){
            rh16[0][j] = __float2half(r0*hreg0);
            rh16[1][j] = __float2half(r1*hreg1);
        }
        __syncthreads();
        float ah0=0.f, ah1=0.f;
        #pragma unroll
        for(int q=0;q<64;q+=4){
            uint4 rv0 = *(const uint4*)(r0p + q);
            uint4 rv1 = *(const uint4*)(r1p + q);
            ah0=d2(wh[q+0],rv0.x,ah0); ah1=d2(wh[q+0],rv1.x,ah1);
            ah0=d2(wh[q+1],rv0.y,ah0); ah1=d2(wh[q+1],rv1.y,ah1);
            ah0=d2(wh[q+2],rv0.z,ah0); ah1=d2(wh[q+2],rv1.z,ah1);
            ah0=d2(wh[q+3],rv0.w,ah0); ah1=d2(wh[q+3],rv1.w,ah1);
        }
        ah0 += __shfl_xor(ah0,1); ah1 += __shfl_xor(ah1,1);
        float ht0 = tanhf_(__half2float(pxcur[512    + j]) + ah0);
        float ht1 = tanhf_(__half2float(pxcur[768+512+j]) + ah1);
        hreg0 = (1.f - z0)*hreg0 + z0*ht0;
        hreg1 = (1.f - z1)*hreg1 + z1*ht1;
        if(kh==0){
            h16[0][j] = __float2half(hreg0);
            h16[1][j] = __float2half(hreg1);
        }
        if(s < Tc-1){
            pxs[cur^1][t] = nf0;
            if(t < 256) pxs[cur^1][t+512] = nf1;
        }
        __syncthreads();
    }
    if(kh==0){
        hstate[(b0+0)*HH + j] = hreg0;
        hstate[(b0+1)*HH + j] = hreg1;
    }
}

// ---- LayerNorm + output projection ----
__global__ __launch_bounds__(256) void k_lnout(const float* __restrict__ hbuf,
    const float* __restrict__ lng, const float* __restrict__ lnb,
    const float* __restrict__ Wo, const float* __restrict__ bo,
    float* __restrict__ out){
    __shared__ __align__(16) float ln_s[HH];
    __shared__ float red[8];
    const int b = blockIdx.x, j = threadIdx.x;
    const float v = hbuf[(long)b*HH + j];
    float s = v, ss = v*v;
    const int lane = j & 63, w = j >> 6;
    for(int off=32; off>0; off>>=1){
        s  += __shfl_down(s,  off);
        ss += __shfl_down(ss, off);
    }
    if(lane == 0){ red[w] = s; red[4+w] = ss; }
    __syncthreads();
    float tot  = red[0]+red[1]+red[2]+red[3];
    float tot2 = red[4]+red[5]+red[6]+red[7];
    float mu  = tot  * (1.0f/HH);
    float var = tot2 * (1.0f/HH) - mu*mu;
    float rstd = rsqrtf(var + 1e-5f);
    ln_s[j] = (v - mu)*rstd*lng[j] + lnb[j];
    __syncthreads();
    if(j < OO){
        float acc = bo[j];
        const float4* w4 = (const float4*)(Wo + j*HH);
        const float4* l4 = (const float4*)ln_s;
        for(int k4=0;k4<HH/4;++k4){
            float4 wv = w4[k4], c = l4[k4];
            acc += wv.x*c.x + wv.y*c.y + wv.z*c.z + wv.w*c.w;
        }
        out[(long)b*OO + j] = acc;
    }
}

// ================= fallback path (round-0, proven, ~68MB ws) =================

__global__ __launch_bounds__(128) void k_emb_o(const float* __restrict__ x,
                                               const float* __restrict__ W,
                                               const float* __restrict__ bias,
                                               float* __restrict__ x1){
    __shared__ __align__(16) float xs[8][DD];
    const int j = threadIdx.x;
    const long row0 = (long)blockIdx.x * 32;
    const float bj = bias[j];
    const float4* W4 = (const float4*)(W + j*DD);
    for(int g=0; g<4; ++g){
        const long rbase = row0 + g*8;
        for(int r=0;r<8;++r) xs[r][j] = x[(rbase+r)*DD + j];
        __syncthreads();
        float acc[8];
        #pragma unroll
        for(int r=0;r<8;++r) acc[r] = bj;
        for(int k4=0;k4<DD/4;++k4){
            float4 w = W4[k4];
            #pragma unroll
            for(int r=0;r<8;++r){
                float4 c = ((const float4*)xs[r])[k4];
                acc[r] += c.x*w.x + c.y*w.y + c.z*w.z + c.w*w.w;
            }
        }
        for(int r=0;r<8;++r) x1[(rbase+r)*DD + j] = acc[r];
        __syncthreads();
    }
}

__global__ __launch_bounds__(128) void k_mean_o(const float* __restrict__ x1,
                                                float* __restrict__ xmean){
    const int j = threadIdx.x;
    const int b = blockIdx.x;
    const float* p = x1 + (long)b*TT*DD + j;
    float s = 0.f;
    for(int t=0;t<TT;++t) s += p[(long)t*DD];
    xmean[b*DD + j] = s * (1.0f/TT);
}

__global__ __launch_bounds__(128) void k_gate_o(float* __restrict__ xf,
    const float* __restrict__ xmask, const float* __restrict__ xdelta,
    const float* __restrict__ noise,
    const float* __restrict__ Wd1, const float* __restrict__ bd1,
    const float* __restrict__ Wd2, const float* __restrict__ bd2,
    const float* __restrict__ Wc,  const float* __restrict__ bc,
    const float* __restrict__ xmean){
    __shared__ __align__(16) float ds[8][DD];
    __shared__ __align__(16) float t1s[8][DD];
    __shared__ __align__(16) float xhs[8][DD];
    const int j = threadIdx.x;
    const long row0 = (long)blockIdx.x * 32;
    const int b = (int)(row0 >> 8);
    const float xm = xmean[b*DD + j];
    const float b1 = bd1[j], b2 = bd2[j], bcj = bc[j];
    const float4* Wd1_4 = (const float4*)(Wd1 + j*DD);
    const float4* Wd2_4 = (const float4*)(Wd2 + j*DD);
    const float4* Wc_4  = (const float4*)(Wc  + j*2*DD);
    for(int g=0; g<4; ++g){
        const long rbase = row0 + g*8;
        for(int r=0;r<8;++r)
            ds[r][j] = fminf(fmaxf(xdelta[(rbase+r)*DD + j], 0.f), 100.f);
        __syncthreads();
        float acc[8];
        #pragma unroll
        for(int r=0;r<8;++r) acc[r] = b1;
        for(int k4=0;k4<DD/4;++k4){
            float4 w = Wd1_4[k4];
            #pragma unroll
            for(int r=0;r<8;++r){
                float4 c = ((const float4*)ds[r])[k4];
                acc[r] += c.x*w.x + c.y*w.y + c.z*w.z + c.w*w.w;
            }
        }
        for(int r=0;r<8;++r) t1s[r][j] = fmaxf(acc[r], 0.f);
        __syncthreads();
        #pragma unroll
        for(int r=0;r<8;++r) acc[r] = b2;
        for(int k4=0;k4<DD/4;++k4){
            float4 w = Wd2_4[k4];
            #pragma unroll
            for(int r=0;r<8;++r){
                float4 c = ((const float4*)t1s[r])[k4];
                acc[r] += c.x*w.x + c.y*w.y + c.z*w.z + c.w*w.w;
            }
        }
        for(int r=0;r<8;++r){
            float gmm = sigmoidf_(acc[r]);
            float m  = xmask[(rbase+r)*DD + j];
            float xv = xf[(rbase+r)*DD + j];
            xhs[r][j] = m*xv + (1.f-m)*gmm*xm;
        }
        __syncthreads();
        #pragma unroll
        for(int r=0;r<8;++r) acc[r] = bcj;
        for(int k4=0;k4<DD/4;++k4){
            float4 w = Wc_4[k4];
            #pragma unroll
            for(int r=0;r<8;++r){
                float4 c = ((const float4*)xhs[r])[k4];
                acc[r] += c.x*w.x + c.y*w.y + c.z*w.z + c.w*w.w;
            }
        }
        for(int k4=0;k4<DD/4;++k4){
            float4 w = Wc_4[DD/4 + k4];
            #pragma unroll
            for(int r=0;r<8;++r){
                float4 c = ((const float4*)ds[r])[k4];
                acc[r] += c.x*w.x + c.y*w.y + c.z*w.z + c.w*w.w;
            }
        }
        for(int r=0;r<8;++r){
            float conf = sigmoidf_(acc[r]);
            float xh = xhs[r][j];
            float nz = noise[(rbase+r)*DD + j];
            xf[(rbase+r)*DD + j] = xh*conf + nz*(1.f-conf);
        }
        __syncthreads();
    }
}

__global__ __launch_bounds__(1024) void k_gru_o(const float* __restrict__ xf,
    const float* __restrict__ xmask, const float* __restrict__ xdelta,
    const float* __restrict__ Wz, const float* __restrict__ bz,
    const float* __restrict__ Wr, const float* __restrict__ br,
    const float* __restrict__ Wh, const float* __restrict__ bh,
    float* __restrict__ hout){
    __shared__ __align__(16) float xcs[4][KH];
    __shared__ __align__(16) float rh[4][HH];
    const int tid = threadIdx.x;
    const int j  = tid & 255;
    const int bl = tid >> 8;
    const long bbase = (long)blockIdx.x * 4;
    xcs[bl][384 + j] = 0.f;
    const float bzj = bz[j], brj = br[j], bhj = bh[j];
    const float4* Wz4 = (const float4*)(Wz + (long)j*KH);
    const float4* Wr4 = (const float4*)(Wr + (long)j*KH);
    const float4* Wh4 = (const float4*)(Wh + (long)j*KH);
    __syncthreads();
    for(int t=0;t<TT;++t){
        if(tid < 4*DD){
            int sb = tid >> 7, k = tid & 127;
            long row = (bbase + sb)*TT + t;
            xcs[sb][k]       = xf[row*DD + k];
            xcs[sb][128 + k] = xmask[row*DD + k];
            xcs[sb][256 + k] = fminf(fmaxf(xdelta[row*DD + k], 0.f), 100.f);
        }
        __syncthreads();
        const float4* cb = (const float4*)xcs[bl];
        float az = bzj, ar = brj;
        for(int k4=0;k4<KH/4;++k4){
            float4 wz = Wz4[k4], wrr = Wr4[k4];
            float4 v = cb[k4];
            az += v.x*wz.x + v.y*wz.y + v.z*wz.z + v.w*wz.w;
            ar += v.x*wrr.x + v.y*wrr.y + v.z*wrr.z + v.w*wrr.w;
        }
        float z = sigmoidf_(az);
        float r = sigmoidf_(ar);
        rh[bl][j] = r * xcs[bl][384 + j];
        __syncthreads();
        float ah = bhj;
        for(int k4=0;k4<96;++k4){
            float4 wh = Wh4[k4];
            float4 v = cb[k4];
            ah += v.x*wh.x + v.y*wh.y + v.z*wh.z + v.w*wh.w;
        }
        const float4* rp = (const float4*)rh[bl];
        for(int k4=0;k4<64;++k4){
            float4 wh = Wh4[96 + k4];
            float4 v = rp[k4];
            ah += v.x*wh.x + v.y*wh.y + v.z*wh.z + v.w*wh.w;
        }
        float ht = tanhf(ah);
        float hold = xcs[bl][384 + j];
        float hn = (1.f - z)*hold + z*ht;
        xcs[bl][384 + j] = hn;
        __syncthreads();
    }
    hout[(bbase + bl)*HH + j] = xcs[bl][384 + j];
}

// ================= launch =================

extern "C" void kernel_launch(void* const* d_in, const int* in_sizes, int n_in,
                              void* d_out, int out_size, void* d_ws, size_t ws_size,
                              hipStream_t stream){
    const float* x      = (const float*)d_in[0];
    const float* xmask  = (const float*)d_in[1];
    const float* xdelta = (const float*)d_in[2];
    const float* noise  = (const float*)d_in[3];
    const float* W_emb  = (const float*)d_in[4];
    const float* b_emb  = (const float*)d_in[5];
    const float* W_d1   = (const float*)d_in[6];
    const float* b_d1   = (const float*)d_in[7];
    const float* W_d2   = (const float*)d_in[8];
    const float* b_d2   = (const float*)d_in[9];
    const float* W_c    = (const float*)d_in[10];
    const float* b_c    = (const float*)d_in[11];
    const float* W_z    = (const float*)d_in[12];
    const float* b_z    = (const float*)d_in[13];
    const float* W_r    = (const float*)d_in[14];
    const float* b_r    = (const float*)d_in[15];
    const float* W_h    = (const float*)d_in[16];
    const float* b_h    = (const float*)d_in[17];
    const float* ln_g   = (const float*)d_in[18];
    const float* ln_b   = (const float*)d_in[19];
    const float* W_o    = (const float*)d_in[20];
    const float* b_o    = (const float*)d_in[21];
    float* out = (float*)d_out;
    char* ws = (char*)d_ws;

    int Tc = 0, lTc = 0;
    {
        const int cand[3]  = {128, 64, 32};
        const int lcand[3] = {7, 6, 5};
        for(int i=0;i<3;++i){
            size_t need = SZ_XC + (size_t)cand[i]*786432 + TAIL_SZ;
            if(ws_size >= need){ Tc = cand[i]; lTc = lcand[i]; break; }
        }
    }

    if(Tc > 0){
        __half* xc    = (__half*)(ws);
        char*   p     = ws + SZ_XC;
        __half* pxc   = (__half*)p;              p += (size_t)Tc*786432;
        __half* Wcat  = (__half*)p;              p += 589824;
        __half* Wrec  = (__half*)p;              p += 393216;
        float*  bcat  = (float*)p;               p += 3072;
        float*  xmean = (float*)p;               p += 262144;
        float*  hstate= (float*)p;               p += 524288;
        __half* Wembh = (__half*)p;              p += 32768;
        __half* Wd1h  = (__half*)p;              p += 32768;
        __half* Wd2h  = (__half*)p;              p += 32768;
        __half* Wch   = (__half*)p;

        k_wprep<<<dim3(768),   dim3(128), 0, stream>>>(W_z,W_r,W_h,b_z,b_r,b_h, Wcat, Wrec, bcat);
        k_cvt  <<<dim3(128),   dim3(256), 0, stream>>>(W_emb, W_d1, W_d2, W_c, Wembh, Wd1h, Wd2h, Wch);
        k_embm <<<dim3(BT/128),dim3(256), 0, stream>>>(x, Wembh, b_emb, xc);
        k_meanv<<<dim3(BB),    dim3(256), 0, stream>>>(xc, xmean);
        k_gatem<<<dim3(BT/128),dim3(256), 0, stream>>>(xc, xmask, xdelta, noise,
                                                       Wd1h,b_d1,Wd2h,b_d2,Wch,b_c, xmean);
        const int nchunk = TT / Tc;
        for(int c=0; c<nchunk; ++c){
            k_projm<<<dim3(BB*Tc/128, 6), dim3(256), 0, stream>>>(xc, Wcat, bcat, pxc, lTc, c);
            k_gruc <<<dim3(BB/2), dim3(512), 0, stream>>>(pxc, Wrec, hstate, Tc, c==0 ? 1 : 0);
        }
        k_lnout<<<dim3(BB), dim3(256), 0, stream>>>(hstate, ln_g, ln_b, W_o, b_o, out);
    } else {
        float* xf    = (float*)ws;
        float* xmean = (float*)(ws + (size_t)BT*DD*4);
        float* hbuf  = (float*)(ws + (size_t)BT*DD*4 + (size_t)BB*DD*4);
        k_emb_o  <<<dim3(BT/32), dim3(128), 0, stream>>>(x, W_emb, b_emb, xf);
        k_mean_o <<<dim3(BB),    dim3(128), 0, stream>>>(xf, xmean);
        k_gate_o <<<dim3(BT/32), dim3(128), 0, stream>>>(xf, xmask, xdelta, noise,
                                                         W_d1,b_d1,W_d2,b_d2,W_c,b_c, xmean);
        k_gru_o  <<<dim3(BB/4),  dim3(1024),0, stream>>>(xf, xmask, xdelta,
                                                         W_z,b_z,W_r,b_r,W_h,b_h, hbuf);
        k_lnout  <<<dim3(BB),    dim3(256), 0, stream>>>(hbuf, ln_g, ln_b, W_o, b_o, out);
    }
}

// Round 6
// 1334.299 us; speedup vs baseline: 44.1873x; 1.0401x over previous
//
#include <hip/hip_runtime.h>
#include <hip/hip_fp16.h>
#include <math.h>

#define BB 512
#define TT 256
#define DD 128
#define HH 256
#define OO 128
#define KH 640   // 3*D + H
#define BT (BB*TT)

typedef unsigned int uint_t;
typedef _Float16 f16x8 __attribute__((ext_vector_type(8)));
typedef float f32x4 __attribute__((ext_vector_type(4)));

__device__ __forceinline__ float sigmoidf_(float x){ return 1.0f/(1.0f+__expf(-x)); }
__device__ __forceinline__ float tanhf_(float x){ float e = __expf(-2.0f*x); return 2.0f/(1.0f+e) - 1.0f; }
__device__ __forceinline__ float clipd_(float x){ return fminf(fmaxf(x, 0.f), 100.f); }

typedef _Float16 h2v __attribute__((ext_vector_type(2)));
__device__ __forceinline__ float d2(uint_t a, uint_t b, float c){
#if __has_builtin(__builtin_amdgcn_fdot2)
    return __builtin_amdgcn_fdot2(__builtin_bit_cast(h2v, a), __builtin_bit_cast(h2v, b), c, false);
#else
    __half2 ha = __builtin_bit_cast(__half2, a);
    __half2 hb = __builtin_bit_cast(__half2, b);
    return c + __half2float(ha.x)*__half2float(hb.x) + __half2float(ha.y)*__half2float(hb.y);
#endif
}
__device__ __forceinline__ uint_t pack2(float a, float b){
    __half2 h; h.x = __float2half(a); h.y = __float2half(b);
    return __builtin_bit_cast(uint_t, h);
}

// ---- ws layout ----
static const size_t SZ_XC   = (size_t)BT*384*2;
static const size_t TAIL_SZ = 589824 + 393216 + 3072 + 262144 + 524288 + 32768*3 + 65536;

// ---- weight prep: GRU weights f32 -> f16, split cat(384)/rec(256) ----
__global__ __launch_bounds__(128) void k_wprep(const float* __restrict__ Wz, const float* __restrict__ Wr,
                                               const float* __restrict__ Wh, const float* __restrict__ bz,
                                               const float* __restrict__ br, const float* __restrict__ bh,
                                               __half* __restrict__ Wcat, __half* __restrict__ Wrec,
                                               float* __restrict__ bcat){
    int gj = blockIdx.x; int j = gj & 255;
    const float* src  = (gj < 256 ? Wz : (gj < 512 ? Wr : Wh)) + (size_t)j*KH;
    const float* bsrc = (gj < 256 ? bz : (gj < 512 ? br : bh));
    for(int k=threadIdx.x; k<384; k+=128) Wcat[(size_t)gj*384 + k] = __float2half(src[k]);
    for(int k=threadIdx.x; k<256; k+=128) Wrec[(size_t)gj*256 + k] = __float2half(src[384+k]);
    if(threadIdx.x==0) bcat[gj] = bsrc[j];
}

// ---- small weights f32 -> f16 ----
__global__ __launch_bounds__(256) void k_cvt(const float* __restrict__ a, const float* __restrict__ b,
                                             const float* __restrict__ c, const float* __restrict__ d,
                                             __half* __restrict__ oa, __half* __restrict__ ob,
                                             __half* __restrict__ oc, __half* __restrict__ od){
    int i = blockIdx.x*256 + threadIdx.x;
    if(i < 16384){
        oa[i] = __float2half(a[i]);
        ob[i] = __float2half(b[i]);
        oc[i] = __float2half(c[i]);
    }
    od[i] = __float2half(d[i]);
}

// ---- MFMA emb: x1 = x @ Wemb^T + b -> xc[.,0:128] ----
__global__ __launch_bounds__(256,4) void k_embm(const float* __restrict__ x,
                                                const __half* __restrict__ Wh,
                                                const float* __restrict__ bias,
                                                __half* __restrict__ xc){
    __shared__ __align__(16) uint4 TxU[128*16];
    const int tid = threadIdx.x;
    const long row0 = (long)blockIdx.x*128;
    {
        const int srow = tid>>1, shalf = tid&1;
        const long gr = row0 + srow;
        const float4* gx = (const float4*)(x + gr*DD + shalf*64);
        #pragma unroll
        for(int u=0;u<8;++u){
            float4 a = gx[u*2], q = gx[u*2+1];
            uint4 pk;
            pk.x = pack2(a.x,a.y); pk.y = pack2(a.z,a.w);
            pk.z = pack2(q.x,q.y); pk.w = pack2(q.z,q.w);
            int unit = shalf*8 + u;
            TxU[srow*16 + (unit ^ (srow&7))] = pk;
        }
    }
    __syncthreads();
    const int wv = tid>>6, lane = tid&63, g = lane>>4, r16 = lane&15;
    const int wrow0 = wv*32;
    const uint4* WU = (const uint4*)Wh;
    f32x4 acc[2][8];
    #pragma unroll
    for(int i=0;i<2;++i)
        #pragma unroll
        for(int jj=0;jj<8;++jj) acc[i][jj] = (f32x4){0.f,0.f,0.f,0.f};
    #pragma unroll
    for(int ks=0;ks<4;++ks){
        f16x8 af[2], bf[8];
        #pragma unroll
        for(int mf=0;mf<2;++mf){
            int rr = wrow0 + mf*16 + r16;
            af[mf] = __builtin_bit_cast(f16x8, TxU[rr*16 + ((ks*4+g) ^ (rr&7))]);
        }
        #pragma unroll
        for(int nf=0;nf<8;++nf){
            int col = nf*16 + r16;
            bf[nf] = __builtin_bit_cast(f16x8, WU[col*16 + ks*4 + g]);
        }
        #pragma unroll
        for(int mf=0;mf<2;++mf)
            #pragma unroll
            for(int nf=0;nf<8;++nf)
                acc[mf][nf] = __builtin_amdgcn_mfma_f32_16x16x32_f16(af[mf], bf[nf], acc[mf][nf], 0,0,0);
    }
    #pragma unroll
    for(int nf=0;nf<8;++nf){
        int col = nf*16 + r16;
        float bb = bias[col];
        #pragma unroll
        for(int mf=0;mf<2;++mf){
            int rowb = wrow0 + mf*16 + g*4;
            f32x4 v = acc[mf][nf];
            #pragma unroll
            for(int e=0;e<4;++e)
                xc[(size_t)(row0+rowb+e)*384 + col] = __float2half(v[e] + bb);
        }
    }
}

// ---- vectorized mean over t of xc[.,0:128] ----
__global__ __launch_bounds__(256) void k_meanv(const __half* __restrict__ xc,
                                               float* __restrict__ xmean){
    __shared__ float red[16][128];
    const int tid = threadIdx.x;
    const int trow = tid>>4, c8 = tid&15;
    const int b = blockIdx.x;
    float s[8];
    #pragma unroll
    for(int e=0;e<8;++e) s[e] = 0.f;
    for(int t=trow; t<TT; t+=16){
        uint4 v = *(const uint4*)(xc + ((size_t)b*TT + t)*384 + c8*8);
        const __half* hp = (const __half*)&v;
        #pragma unroll
        for(int e=0;e<8;++e) s[e] += __half2float(hp[e]);
    }
    #pragma unroll
    for(int e=0;e<8;++e) red[trow][c8*8+e] = s[e];
    __syncthreads();
    if(tid < 128){
        float tot = 0.f;
        #pragma unroll
        for(int r=0;r<16;++r) tot += red[r][tid];
        xmean[b*DD + tid] = tot*(1.0f/TT);
    }
}

// ---- fused MFMA gate chain: fills xc row = [x_final | mask | delta] ----
__global__ __launch_bounds__(256,2) void k_gatem(__half* __restrict__ xc,
    const float* __restrict__ xmask, const float* __restrict__ xdelta,
    const float* __restrict__ noise,
    const __half* __restrict__ Wd1h, const float* __restrict__ bd1,
    const __half* __restrict__ Wd2h, const float* __restrict__ bd2,
    const __half* __restrict__ Wch,  const float* __restrict__ bc,
    const float* __restrict__ xmean){
    __shared__ __align__(16) uint4 TdU[128*16];
    __shared__ __align__(16) uint4 TtU[128*16];
    __half* Tth = (__half*)TtU;
    const int tid = threadIdx.x;
    const long row0 = (long)blockIdx.x*128;
    const int b = (int)(row0 >> 8);

    {
        const int srow = tid>>1, shalf = tid&1;
        const long gr = row0 + srow;
        const float4* gd = (const float4*)(xdelta + gr*DD + shalf*64);
        const float4* gm = (const float4*)(xmask  + gr*DD + shalf*64);
        uint4* xcu = (uint4*)(xc + gr*384);
        #pragma unroll
        for(int u=0;u<8;++u){
            float4 a = gd[u*2], q = gd[u*2+1];
            uint4 pk;
            pk.x = pack2(clipd_(a.x), clipd_(a.y));
            pk.y = pack2(clipd_(a.z), clipd_(a.w));
            pk.z = pack2(clipd_(q.x), clipd_(q.y));
            pk.w = pack2(clipd_(q.z), clipd_(q.w));
            int unit = shalf*8 + u;
            TdU[srow*16 + (unit ^ (srow&7))] = pk;
            xcu[32 + unit] = pk;
        }
        #pragma unroll
        for(int u=0;u<8;++u){
            float4 a = gm[u*2], q = gm[u*2+1];
            uint4 pk;
            pk.x = pack2(a.x,a.y); pk.y = pack2(a.z,a.w);
            pk.z = pack2(q.x,q.y); pk.w = pack2(q.z,q.w);
            xcu[16 + shalf*8 + u] = pk;
        }
    }
    __syncthreads();

    const int wv = tid>>6, lane = tid&63, g = lane>>4, r16 = lane&15;
    const int wrow0 = wv*32;
    const uint4* W1U = (const uint4*)Wd1h;
    const uint4* W2U = (const uint4*)Wd2h;
    const uint4* WcU = (const uint4*)Wch;
    f32x4 acc[2][8];

    // stage 2: t1 = relu(d @ Wd1^T + b1) -> Tt
    #pragma unroll
    for(int i=0;i<2;++i)
        #pragma unroll
        for(int jj=0;jj<8;++jj) acc[i][jj] = (f32x4){0.f,0.f,0.f,0.f};
    #pragma unroll
    for(int ks=0;ks<4;++ks){
        f16x8 af[2], bf[8];
        #pragma unroll
        for(int mf=0;mf<2;++mf){
            int rr = wrow0 + mf*16 + r16;
            af[mf] = __builtin_bit_cast(f16x8, TdU[rr*16 + ((ks*4+g) ^ (rr&7))]);
        }
        #pragma unroll
        for(int nf=0;nf<8;++nf){
            int col = nf*16 + r16;
            bf[nf] = __builtin_bit_cast(f16x8, W1U[col*16 + ks*4 + g]);
        }
        #pragma unroll
        for(int mf=0;mf<2;++mf)
            #pragma unroll
            for(int nf=0;nf<8;++nf)
                acc[mf][nf] = __builtin_amdgcn_mfma_f32_16x16x32_f16(af[mf], bf[nf], acc[mf][nf], 0,0,0);
    }
    #pragma unroll
    for(int nf=0;nf<8;++nf){
        int col = nf*16 + r16;
        float bb = bd1[col];
        int u = col>>3, cl = col&7;
        #pragma unroll
        for(int mf=0;mf<2;++mf){
            int rowb = wrow0 + mf*16 + g*4;
            f32x4 v = acc[mf][nf];
            #pragma unroll
            for(int e=0;e<4;++e){
                int rr = rowb + e;
                float t = v[e] + bb; t = t > 0.f ? t : 0.f;
                Tth[(rr*16 + (u ^ (rr&7)))*8 + cl] = __float2half(t);
            }
        }
    }

    // stage 3: gamma = sigmoid(t1 @ Wd2^T + b2) (own rows only; no barrier)
    #pragma unroll
    for(int i=0;i<2;++i)
        #pragma unroll
        for(int jj=0;jj<8;++jj) acc[i][jj] = (f32x4){0.f,0.f,0.f,0.f};
    #pragma unroll
    for(int ks=0;ks<4;++ks){
        f16x8 af[2], bf[8];
        #pragma unroll
        for(int mf=0;mf<2;++mf){
            int rr = wrow0 + mf*16 + r16;
            af[mf] = __builtin_bit_cast(f16x8, TtU[rr*16 + ((ks*4+g) ^ (rr&7))]);
        }
        #pragma unroll
        for(int nf=0;nf<8;++nf){
            int col = nf*16 + r16;
            bf[nf] = __builtin_bit_cast(f16x8, W2U[col*16 + ks*4 + g]);
        }
        #pragma unroll
        for(int mf=0;mf<2;++mf)
            #pragma unroll
            for(int nf=0;nf<8;++nf)
                acc[mf][nf] = __builtin_amdgcn_mfma_f32_16x16x32_f16(af[mf], bf[nf], acc[mf][nf], 0,0,0);
    }

    // stage 4: x_hat = m*x1 + (1-m)*gamma*xmean -> Tt
    #pragma unroll
    for(int nf=0;nf<8;++nf){
        int col = nf*16 + r16;
        float b2 = bd2[col];
        float xm = xmean[b*DD + col];
        int u = col>>3, cl = col&7;
        #pragma unroll
        for(int mf=0;mf<2;++mf){
            int rowb = wrow0 + mf*16 + g*4;
            f32x4 v = acc[mf][nf];
            #pragma unroll
            for(int e=0;e<4;++e){
                int rr = rowb + e;
                long grow = row0 + rr;
                float m  = xmask[grow*DD + col];
                float x1 = __half2float(xc[grow*384 + col]);
                float gmm = sigmoidf_(v[e] + b2);
                float xh = m*x1 + (1.f-m)*gmm*xm;
                Tth[(rr*16 + (u ^ (rr&7)))*8 + cl] = __float2half(xh);
            }
        }
    }

    // stage 5: conf = sigmoid(xh@Wc[:, :128]^T + d@Wc[:,128:]^T + bc)
    #pragma unroll
    for(int i=0;i<2;++i)
        #pragma unroll
        for(int jj=0;jj<8;++jj) acc[i][jj] = (f32x4){0.f,0.f,0.f,0.f};
    #pragma unroll
    for(int ks=0;ks<4;++ks){
        f16x8 af[2], bf[8];
        #pragma unroll
        for(int mf=0;mf<2;++mf){
            int rr = wrow0 + mf*16 + r16;
            af[mf] = __builtin_bit_cast(f16x8, TtU[rr*16 + ((ks*4+g) ^ (rr&7))]);
        }
        #pragma unroll
        for(int nf=0;nf<8;++nf){
            int col = nf*16 + r16;
            bf[nf] = __builtin_bit_cast(f16x8, WcU[col*32 + ks*4 + g]);
        }
        #pragma unroll
        for(int mf=0;mf<2;++mf)
            #pragma unroll
            for(int nf=0;nf<8;++nf)
                acc[mf][nf] = __builtin_amdgcn_mfma_f32_16x16x32_f16(af[mf], bf[nf], acc[mf][nf], 0,0,0);
    }
    #pragma unroll
    for(int ks=0;ks<4;++ks){
        f16x8 af[2], bf[8];
        #pragma unroll
        for(int mf=0;mf<2;++mf){
            int rr = wrow0 + mf*16 + r16;
            af[mf] = __builtin_bit_cast(f16x8, TdU[rr*16 + ((ks*4+g) ^ (rr&7))]);
        }
        #pragma unroll
        for(int nf=0;nf<8;++nf){
            int col = nf*16 + r16;
            bf[nf] = __builtin_bit_cast(f16x8, WcU[col*32 + 16 + ks*4 + g]);
        }
        #pragma unroll
        for(int mf=0;mf<2;++mf)
            #pragma unroll
            for(int nf=0;nf<8;++nf)
                acc[mf][nf] = __builtin_amdgcn_mfma_f32_16x16x32_f16(af[mf], bf[nf], acc[mf][nf], 0,0,0);
    }

    // stage 6: x_final -> xc[.,0:128]
    #pragma unroll
    for(int nf=0;nf<8;++nf){
        int col = nf*16 + r16;
        float bcc = bc[col];
        int u = col>>3, cl = col&7;
        #pragma unroll
        for(int mf=0;mf<2;++mf){
            int rowb = wrow0 + mf*16 + g*4;
            f32x4 v = acc[mf][nf];
            #pragma unroll
            for(int e=0;e<4;++e){
                int rr = rowb + e;
                long grow = row0 + rr;
                float conf = sigmoidf_(v[e] + bcc);
                float xh = __half2float(Tth[(rr*16 + (u ^ (rr&7)))*8 + cl]);
                float nz = noise[grow*DD + col];
                xc[grow*384 + col] = __float2half(xh*conf + nz*(1.f-conf));
            }
        }
    }
}

// ---- MFMA projection: px[r][768] = xc_chunk[r][0:384] @ Wcat^T + bcat ----
__global__ __launch_bounds__(256) void k_projm(const __half* __restrict__ xc,
                                               const __half* __restrict__ Wcat,
                                               const float* __restrict__ bcat,
                                               __half* __restrict__ px,
                                               int lTc, int chunk){
    __shared__ __align__(16) __half As[128*64];
    __shared__ __align__(16) __half Bs[128*64];
    const int tid = threadIdx.x;
    const int rblk = blockIdx.x * 128;
    const int ct0  = blockIdx.y * 128;
    const int mTc = (1<<lTc) - 1;

    const int row = tid >> 1;
    const int hf  = tid & 1;
    const int ar  = rblk + row;
    const long grow = ((long)(ar >> lTc))*TT + ((long)chunk << lTc) + (ar & mTc);
    const uint4* gA = (const uint4*)(xc + grow*384);
    const uint4* gB = (const uint4*)(Wcat + (size_t)(ct0 + row)*384);
    uint4* AsU = (uint4*)As;
    uint4* BsU = (uint4*)Bs;

    const int wv = tid >> 6;
    const int wm = wv >> 1, wn = wv & 1;
    const int l  = tid & 63;
    const int g  = l >> 4, r16 = l & 15;

    f32x4 acc[4][4];
    #pragma unroll
    for(int i=0;i<4;++i)
        #pragma unroll
        for(int jj=0;jj<4;++jj) acc[i][jj] = (f32x4){0.f,0.f,0.f,0.f};

    for(int bk=0; bk<6; ++bk){
        uint4 av[4], bv[4];
        #pragma unroll
        for(int u=0;u<4;++u){ av[u] = gA[bk*8 + hf*4 + u]; bv[u] = gB[bk*8 + hf*4 + u]; }
        if(bk) __syncthreads();
        #pragma unroll
        for(int u=0;u<4;++u){
            int uu = hf*4 + u;
            AsU[row*8 + (uu ^ (row&7))] = av[u];
            BsU[row*8 + (uu ^ (row&7))] = bv[u];
        }
        __syncthreads();
        #pragma unroll
        for(int ks=0;ks<2;++ks){
            f16x8 af[4], bf[4];
            #pragma unroll
            for(int mf=0;mf<4;++mf){
                int rr = wm*64 + mf*16 + r16;
                af[mf] = __builtin_bit_cast(f16x8, AsU[rr*8 + ((ks*4+g) ^ (rr&7))]);
            }
            #pragma unroll
            for(int nf=0;nf<4;++nf){
                int rr = wn*64 + nf*16 + r16;
                bf[nf] = __builtin_bit_cast(f16x8, BsU[rr*8 + ((ks*4+g) ^ (rr&7))]);
            }
            #pragma unroll
            for(int mf=0;mf<4;++mf)
                #pragma unroll
                for(int nf=0;nf<4;++nf)
                    acc[mf][nf] = __builtin_amdgcn_mfma_f32_16x16x32_f16(af[mf], bf[nf], acc[mf][nf], 0,0,0);
        }
    }
    #pragma unroll
    for(int nf=0; nf<4; ++nf){
        int col = ct0 + wn*64 + nf*16 + r16;
        float bb = bcat[col];
        #pragma unroll
        for(int mf=0; mf<4; ++mf){
            int r0 = rblk + wm*64 + mf*16 + g*4;
            f32x4 v = acc[mf][nf];
            #pragma unroll
            for(int e=0;e<4;++e)
                px[(size_t)(r0+e)*768 + col] = __float2half(v[e] + bb);
        }
    }
}

// ---- chunked GRU: register-resident f16 recurrent weights, 2 rows/block ----
// LDS h/rh: padded layout [row][kh*68 + q] dwords (64 data + 4 pad per kh half)
// so the two per-wave ds_read_b128 addresses (kh=0 / kh=1) hit DISJOINT bank
// groups {q..q+3} vs {q+4..q+7}  (un-padded 64-dword stride aliased to the
// same 4 banks -> 6.7e7 SQ_LDS_BANK_CONFLICT cycles/dispatch in round 5).
__global__ __launch_bounds__(512,2) void k_gruc(const __half* __restrict__ pxc,
                                                const __half* __restrict__ Wrec,
                                                float* __restrict__ hstate,
                                                int Tc, int init){
    __shared__ __align__(16) uint_t hU[2][136];
    __shared__ __align__(16) uint_t rhU[2][136];
    __shared__ __align__(16) uint_t pxs[2][768];
    const int t  = threadIdx.x;
    const int j  = t >> 1;
    const int kh = t & 1;
    const long b0 = (long)blockIdx.x*2;
    const uint_t* Wr32 = (const uint_t*)Wrec;

    uint_t wz[64], wr[64], wh[64];
    #pragma unroll
    for(int q=0;q<64;++q){
        wz[q] = Wr32[(size_t)(      j)*128 + kh*64 + q];
        wr[q] = Wr32[(size_t)(256 + j)*128 + kh*64 + q];
        wh[q] = Wr32[(size_t)(512 + j)*128 + kh*64 + q];
    }

    const uint_t* px32 = (const uint_t*)pxc;
    auto ldpx = [&](int tl, int f)->uint_t{
        int row = (f >= 384); int off = f - row*384;
        return px32[((size_t)(b0+row)*Tc + tl)*384 + off];
    };
    // padded half-index for h value j: region j>>7 (136 halves each), offset j&127
    const int hidx = ((j>>7)*136) + (j&127);

    float hreg0, hreg1;
    if(init){ hreg0 = 0.f; hreg1 = 0.f; }
    else    { hreg0 = hstate[(b0+0)*HH + j]; hreg1 = hstate[(b0+1)*HH + j]; }
    if(kh==0){
        ((__half*)hU[0])[hidx] = __float2half(hreg0);
        ((__half*)hU[1])[hidx] = __float2half(hreg1);
    }
    pxs[0][t] = ldpx(0, t);
    if(t < 256) pxs[0][t+512] = ldpx(0, t+512);
    __syncthreads();

    const uint_t* h0p = hU[0]  + kh*68;
    const uint_t* h1p = hU[1]  + kh*68;
    const uint_t* r0p = rhU[0] + kh*68;
    const uint_t* r1p = rhU[1] + kh*68;

    for(int s=0; s<Tc; ++s){
        const int cur = s & 1;
        uint_t nf0 = 0, nf1 = 0;
        if(s < Tc-1){ nf0 = ldpx(s+1, t); if(t < 256) nf1 = ldpx(s+1, t+512); }

        const __half* pxcur = (const __half*)pxs[cur];
        float az0=0.f, az1=0.f, ar0=0.f, ar1=0.f;
        #pragma unroll
        for(int q=0;q<64;q+=4){
            uint4 hv0 = *(const uint4*)(h0p + q);
            uint4 hv1 = *(const uint4*)(h1p + q);
            az0=d2(wz[q+0],hv0.x,az0); ar0=d2(wr[q+0],hv0.x,ar0); az1=d2(wz[q+0],hv1.x,az1); ar1=d2(wr[q+0],hv1.x,ar1);
            az0=d2(wz[q+1],hv0.y,az0); ar0=d2(wr[q+1],hv0.y,ar0); az1=d2(wz[q+1],hv1.y,az1); ar1=d2(wr[q+1],hv1.y,ar1);
            az0=d2(wz[q+2],hv0.z,az0); ar0=d2(wr[q+2],hv0.z,ar0); az1=d2(wz[q+2],hv1.z,az1); ar1=d2(wr[q+2],hv1.z,ar1);
            az0=d2(wz[q+3],hv0.w,az0); ar0=d2(wr[q+3],hv0.w,ar0); az1=d2(wz[q+3],hv1.w,az1); ar1=d2(wr[q+3],hv1.w,ar1);
        }
        az0 += __shfl_xor(az0,1); az1 += __shfl_xor(az1,1);
        ar0 += __shfl_xor(ar0,1); ar1 += __shfl_xor(ar1,1);
        float z0 = sigmoidf_(__half2float(pxcur[        j]) + az0);
        float z1 = sigmoidf_(__half2float(pxcur[768   + j]) + az1);
        float r0 = sigmoidf_(__half2float(pxcur[256   + j]) + ar0);
        float r1 = sigmoidf_(__half2float(pxcur[768+256+j]) + ar1);
        if(kh==0){
            ((__half*)rhU[0])[hidx] = __float2half(r0*hreg0);
            ((__half*)rhU[1])[hidx] = __float2half(r1*hreg1);
        }
        __syncthreads();
        float ah0=0.f, ah1=0.f;
        #pragma unroll
        for(int q=0;q<64;q+=4){
            uint4 rv0 = *(const uint4*)(r0p + q);
            uint4 rv1 = *(const uint4*)(r1p + q);
            ah0=d2(wh[q+0],rv0.x,ah0); ah1=d2(wh[q+0],rv1.x,ah1);
            ah0=d2(wh[q+1],rv0.y,ah0); ah1=d2(wh[q+1],rv1.y,ah1);
            ah0=d2(wh[q+2],rv0.z,ah0); ah1=d2(wh[q+2],rv1.z,ah1);
            ah0=d2(wh[q+3],rv0.w,ah0); ah1=d2(wh[q+3],rv1.w,ah1);
        }
        ah0 += __shfl_xor(ah0,1); ah1 += __shfl_xor(ah1,1);
        float ht0 = tanhf_(__half2float(pxcur[512    + j]) + ah0);
        float ht1 = tanhf_(__half2float(pxcur[768+512+j]) + ah1);
        hreg0 = (1.f - z0)*hreg0 + z0*ht0;
        hreg1 = (1.f - z1)*hreg1 + z1*ht1;
        if(kh==0){
            ((__half*)hU[0])[hidx] = __float2half(hreg0);
            ((__half*)hU[1])[hidx] = __float2half(hreg1);
        }
        if(s < Tc-1){
            pxs[cur^1][t] = nf0;
            if(t < 256) pxs[cur^1][t+512] = nf1;
        }
        __syncthreads();
    }
    if(kh==0){
        hstate[(b0+0)*HH + j] = hreg0;
        hstate[(b0+1)*HH + j] = hreg1;
    }
}

// ---- LayerNorm + output projection ----
__global__ __launch_bounds__(256) void k_lnout(const float* __restrict__ hbuf,
    const float* __restrict__ lng, const float* __restrict__ lnb,
    const float* __restrict__ Wo, const float* __restrict__ bo,
    float* __restrict__ out){
    __shared__ __align__(16) float ln_s[HH];
    __shared__ float red[8];
    const int b = blockIdx.x, j = threadIdx.x;
    const float v = hbuf[(long)b*HH + j];
    float s = v, ss = v*v;
    const int lane = j & 63, w = j >> 6;
    for(int off=32; off>0; off>>=1){
        s  += __shfl_down(s,  off);
        ss += __shfl_down(ss, off);
    }
    if(lane == 0){ red[w] = s; red[4+w] = ss; }
    __syncthreads();
    float tot  = red[0]+red[1]+red[2]+red[3];
    float tot2 = red[4]+red[5]+red[6]+red[7];
    float mu  = tot  * (1.0f/HH);
    float var = tot2 * (1.0f/HH) - mu*mu;
    float rstd = rsqrtf(var + 1e-5f);
    ln_s[j] = (v - mu)*rstd*lng[j] + lnb[j];
    __syncthreads();
    if(j < OO){
        float acc = bo[j];
        const float4* w4 = (const float4*)(Wo + j*HH);
        const float4* l4 = (const float4*)ln_s;
        for(int k4=0;k4<HH/4;++k4){
            float4 wv = w4[k4], c = l4[k4];
            acc += wv.x*c.x + wv.y*c.y + wv.z*c.z + wv.w*c.w;
        }
        out[(long)b*OO + j] = acc;
    }
}

// ================= fallback path (round-0, proven, ~68MB ws) =================

__global__ __launch_bounds__(128) void k_emb_o(const float* __restrict__ x,
                                               const float* __restrict__ W,
                                               const float* __restrict__ bias,
                                               float* __restrict__ x1){
    __shared__ __align__(16) float xs[8][DD];
    const int j = threadIdx.x;
    const long row0 = (long)blockIdx.x * 32;
    const float bj = bias[j];
    const float4* W4 = (const float4*)(W + j*DD);
    for(int g=0; g<4; ++g){
        const long rbase = row0 + g*8;
        for(int r=0;r<8;++r) xs[r][j] = x[(rbase+r)*DD + j];
        __syncthreads();
        float acc[8];
        #pragma unroll
        for(int r=0;r<8;++r) acc[r] = bj;
        for(int k4=0;k4<DD/4;++k4){
            float4 w = W4[k4];
            #pragma unroll
            for(int r=0;r<8;++r){
                float4 c = ((const float4*)xs[r])[k4];
                acc[r] += c.x*w.x + c.y*w.y + c.z*w.z + c.w*w.w;
            }
        }
        for(int r=0;r<8;++r) x1[(rbase+r)*DD + j] = acc[r];
        __syncthreads();
    }
}

__global__ __launch_bounds__(128) void k_mean_o(const float* __restrict__ x1,
                                                float* __restrict__ xmean){
    const int j = threadIdx.x;
    const int b = blockIdx.x;
    const float* p = x1 + (long)b*TT*DD + j;
    float s = 0.f;
    for(int t=0;t<TT;++t) s += p[(long)t*DD];
    xmean[b*DD + j] = s * (1.0f/TT);
}

__global__ __launch_bounds__(128) void k_gate_o(float* __restrict__ xf,
    const float* __restrict__ xmask, const float* __restrict__ xdelta,
    const float* __restrict__ noise,
    const float* __restrict__ Wd1, const float* __restrict__ bd1,
    const float* __restrict__ Wd2, const float* __restrict__ bd2,
    const float* __restrict__ Wc,  const float* __restrict__ bc,
    const float* __restrict__ xmean){
    __shared__ __align__(16) float ds[8][DD];
    __shared__ __align__(16) float t1s[8][DD];
    __shared__ __align__(16) float xhs[8][DD];
    const int j = threadIdx.x;
    const long row0 = (long)blockIdx.x * 32;
    const int b = (int)(row0 >> 8);
    const float xm = xmean[b*DD + j];
    const float b1 = bd1[j], b2 = bd2[j], bcj = bc[j];
    const float4* Wd1_4 = (const float4*)(Wd1 + j*DD);
    const float4* Wd2_4 = (const float4*)(Wd2 + j*DD);
    const float4* Wc_4  = (const float4*)(Wc  + j*2*DD);
    for(int g=0; g<4; ++g){
        const long rbase = row0 + g*8;
        for(int r=0;r<8;++r)
            ds[r][j] = fminf(fmaxf(xdelta[(rbase+r)*DD + j], 0.f), 100.f);
        __syncthreads();
        float acc[8];
        #pragma unroll
        for(int r=0;r<8;++r) acc[r] = b1;
        for(int k4=0;k4<DD/4;++k4){
            float4 w = Wd1_4[k4];
            #pragma unroll
            for(int r=0;r<8;++r){
                float4 c = ((const float4*)ds[r])[k4];
                acc[r] += c.x*w.x + c.y*w.y + c.z*w.z + c.w*w.w;
            }
        }
        for(int r=0;r<8;++r) t1s[r][j] = fmaxf(acc[r], 0.f);
        __syncthreads();
        #pragma unroll
        for(int r=0;r<8;++r) acc[r] = b2;
        for(int k4=0;k4<DD/4;++k4){
            float4 w = Wd2_4[k4];
            #pragma unroll
            for(int r=0;r<8;++r){
                float4 c = ((const float4*)t1s[r])[k4];
                acc[r] += c.x*w.x + c.y*w.y + c.z*w.z + c.w*w.w;
            }
        }
        for(int r=0;r<8;++r){
            float gmm = sigmoidf_(acc[r]);
            float m  = xmask[(rbase+r)*DD + j];
            float xv = xf[(rbase+r)*DD + j];
            xhs[r][j] = m*xv + (1.f-m)*gmm*xm;
        }
        __syncthreads();
        #pragma unroll
        for(int r=0;r<8;++r) acc[r] = bcj;
        for(int k4=0;k4<DD/4;++k4){
            float4 w = Wc_4[k4];
            #pragma unroll
            for(int r=0;r<8;++r){
                float4 c = ((const float4*)xhs[r])[k4];
                acc[r] += c.x*w.x + c.y*w.y + c.z*w.z + c.w*w.w;
            }
        }
        for(int k4=0;k4<DD/4;++k4){
            float4 w = Wc_4[DD/4 + k4];
            #pragma unroll
            for(int r=0;r<8;++r){
                float4 c = ((const float4*)ds[r])[k4];
                acc[r] += c.x*w.x + c.y*w.y + c.z*w.z + c.w*w.w;
            }
        }
        for(int r=0;r<8;++r){
            float conf = sigmoidf_(acc[r]);
            float xh = xhs[r][j];
            float nz = noise[(rbase+r)*DD + j];
            xf[(rbase+r)*DD + j] = xh*conf + nz*(1.f-conf);
        }
        __syncthreads();
    }
}

__global__ __launch_bounds__(1024) void k_gru_o(const float* __restrict__ xf,
    const float* __restrict__ xmask, const float* __restrict__ xdelta,
    const float* __restrict__ Wz, const float* __restrict__ bz,
    const float* __restrict__ Wr, const float* __restrict__ br,
    const float* __restrict__ Wh, const float* __restrict__ bh,
    float* __restrict__ hout){
    __shared__ __align__(16) float xcs[4][KH];
    __shared__ __align__(16) float rh[4][HH];
    const int tid = threadIdx.x;
    const int j  = tid & 255;
    const int bl = tid >> 8;
    const long bbase = (long)blockIdx.x * 4;
    xcs[bl][384 + j] = 0.f;
    const float bzj = bz[j], brj = br[j], bhj = bh[j];
    const float4* Wz4 = (const float4*)(Wz + (long)j*KH);
    const float4* Wr4 = (const float4*)(Wr + (long)j*KH);
    const float4* Wh4 = (const float4*)(Wh + (long)j*KH);
    __syncthreads();
    for(int t=0;t<TT;++t){
        if(tid < 4*DD){
            int sb = tid >> 7, k = tid & 127;
            long row = (bbase + sb)*TT + t;
            xcs[sb][k]       = xf[row*DD + k];
            xcs[sb][128 + k] = xmask[row*DD + k];
            xcs[sb][256 + k] = fminf(fmaxf(xdelta[row*DD + k], 0.f), 100.f);
        }
        __syncthreads();
        const float4* cb = (const float4*)xcs[bl];
        float az = bzj, ar = brj;
        for(int k4=0;k4<KH/4;++k4){
            float4 wz = Wz4[k4], wrr = Wr4[k4];
            float4 v = cb[k4];
            az += v.x*wz.x + v.y*wz.y + v.z*wz.z + v.w*wz.w;
            ar += v.x*wrr.x + v.y*wrr.y + v.z*wrr.z + v.w*wrr.w;
        }
        float z = sigmoidf_(az);
        float r = sigmoidf_(ar);
        rh[bl][j] = r * xcs[bl][384 + j];
        __syncthreads();
        float ah = bhj;
        for(int k4=0;k4<96;++k4){
            float4 wh = Wh4[k4];
            float4 v = cb[k4];
            ah += v.x*wh.x + v.y*wh.y + v.z*wh.z + v.w*wh.w;
        }
        const float4* rp = (const float4*)rh[bl];
        for(int k4=0;k4<64;++k4){
            float4 wh = Wh4[96 + k4];
            float4 v = rp[k4];
            ah += v.x*wh.x + v.y*wh.y + v.z*wh.z + v.w*wh.w;
        }
        float ht = tanhf(ah);
        float hold = xcs[bl][384 + j];
        float hn = (1.f - z)*hold + z*ht;
        xcs[bl][384 + j] = hn;
        __syncthreads();
    }
    hout[(bbase + bl)*HH + j] = xcs[bl][384 + j];
}

// ================= launch =================

extern "C" void kernel_launch(void* const* d_in, const int* in_sizes, int n_in,
                              void* d_out, int out_size, void* d_ws, size_t ws_size,
                              hipStream_t stream){
    const float* x      = (const float*)d_in[0];
    const float* xmask  = (const float*)d_in[1];
    const float* xdelta = (const float*)d_in[2];
    const float* noise  = (const float*)d_in[3];
    const float* W_emb  = (const float*)d_in[4];
    const float* b_emb  = (const float*)d_in[5];
    const float* W_d1   = (const float*)d_in[6];
    const float* b_d1   = (const float*)d_in[7];
    const float* W_d2   = (const float*)d_in[8];
    const float* b_d2   = (const float*)d_in[9];
    const float* W_c    = (const float*)d_in[10];
    const float* b_c    = (const float*)d_in[11];
    const float* W_z    = (const float*)d_in[12];
    const float* b_z    = (const float*)d_in[13];
    const float* W_r    = (const float*)d_in[14];
    const float* b_r    = (const float*)d_in[15];
    const float* W_h    = (const float*)d_in[16];
    const float* b_h    = (const float*)d_in[17];
    const float* ln_g   = (const float*)d_in[18];
    const float* ln_b   = (const float*)d_in[19];
    const float* W_o    = (const float*)d_in[20];
    const float* b_o    = (const float*)d_in[21];
    float* out = (float*)d_out;
    char* ws = (char*)d_ws;

    int Tc = 0, lTc = 0;
    {
        const int cand[3]  = {128, 64, 32};
        const int lcand[3] = {7, 6, 5};
        for(int i=0;i<3;++i){
            size_t need = SZ_XC + (size_t)cand[i]*786432 + TAIL_SZ;
            if(ws_size >= need){ Tc = cand[i]; lTc = lcand[i]; break; }
        }
    }

    if(Tc > 0){
        __half* xc    = (__half*)(ws);
        char*   p     = ws + SZ_XC;
        __half* pxc   = (__half*)p;              p += (size_t)Tc*786432;
        __half* Wcat  = (__half*)p;              p += 589824;
        __half* Wrec  = (__half*)p;              p += 393216;
        float*  bcat  = (float*)p;               p += 3072;
        float*  xmean = (float*)p;               p += 262144;
        float*  hstate= (float*)p;               p += 524288;
        __half* Wembh = (__half*)p;              p += 32768;
        __half* Wd1h  = (__half*)p;              p += 32768;
        __half* Wd2h  = (__half*)p;              p += 32768;
        __half* Wch   = (__half*)p;

        k_wprep<<<dim3(768),   dim3(128), 0, stream>>>(W_z,W_r,W_h,b_z,b_r,b_h, Wcat, Wrec, bcat);
        k_cvt  <<<dim3(128),   dim3(256), 0, stream>>>(W_emb, W_d1, W_d2, W_c, Wembh, Wd1h, Wd2h, Wch);
        k_embm <<<dim3(BT/128),dim3(256), 0, stream>>>(x, Wembh, b_emb, xc);
        k_meanv<<<dim3(BB),    dim3(256), 0, stream>>>(xc, xmean);
        k_gatem<<<dim3(BT/128),dim3(256), 0, stream>>>(xc, xmask, xdelta, noise,
                                                       Wd1h,b_d1,Wd2h,b_d2,Wch,b_c, xmean);
        const int nchunk = TT / Tc;
        for(int c=0; c<nchunk; ++c){
            k_projm<<<dim3(BB*Tc/128, 6), dim3(256), 0, stream>>>(xc, Wcat, bcat, pxc, lTc, c);
            k_gruc <<<dim3(BB/2), dim3(512), 0, stream>>>(pxc, Wrec, hstate, Tc, c==0 ? 1 : 0);
        }
        k_lnout<<<dim3(BB), dim3(256), 0, stream>>>(hstate, ln_g, ln_b, W_o, b_o, out);
    } else {
        float* xf    = (float*)ws;
        float* xmean = (float*)(ws + (size_t)BT*DD*4);
        float* hbuf  = (float*)(ws + (size_t)BT*DD*4 + (size_t)BB*DD*4);
        k_emb_o  <<<dim3(BT/32), dim3(128), 0, stream>>>(x, W_emb, b_emb, xf);
        k_mean_o <<<dim3(BB),    dim3(128), 0, stream>>>(xf, xmean);
        k_gate_o <<<dim3(BT/32), dim3(128), 0, stream>>>(xf, xmask, xdelta, noise,
                                                         W_d1,b_d1,W_d2,b_d2,W_c,b_c, xmean);
        k_gru_o  <<<dim3(BB/4),  dim3(1024),0, stream>>>(xf, xmask, xdelta,
                                                         W_z,b_z,W_r,b_r,W_h,b_h, hbuf);
        k_lnout  <<<dim3(BB),    dim3(256), 0, stream>>>(hbuf, ln_g, ln_b, W_o, b_o, out);
    }
}